// Round 1
// baseline (2996.957 us; speedup 1.0000x reference)
//
#include <hip/hip_runtime.h>
#include <hip/hip_bf16.h>
#include <math.h>

#define B_ 128
#define T_ 128
#define E_ 1024
#define IN_ 1074
#define H_ 256
#define G3_ 768
#define D_ 512
#define CO_ 256

// ---------------- prep kernels ----------------

// me[dir][m][g] = bih[g] + sum_c mask_emb[m][c] * Wih[g][1024+c]
__global__ void k_prep_me(const float* __restrict__ mask_emb,
                          const float* __restrict__ Wf, const float* __restrict__ bf,
                          const float* __restrict__ Wb, const float* __restrict__ bb,
                          float* __restrict__ me) {
    int idx = blockIdx.x * 256 + threadIdx.x;   // 0..3071
    if (idx >= 2 * 2 * G3_) return;
    int dir = idx / (2 * G3_);
    int rem = idx % (2 * G3_);
    int m = rem / G3_;
    int g = rem % G3_;
    const float* W = dir ? Wb : Wf;
    const float* bi = dir ? bb : bf;
    float acc = bi[g];
    const float* wrow = W + (size_t)g * IN_ + E_;
    const float* e = mask_emb + m * 50;
    #pragma unroll 10
    for (int c = 0; c < 50; ++c) acc += e[c] * wrow[c];
    me[idx] = acc;
}

// WT[k][g] = Whh[g][k]   (per direction)
__global__ void k_tr_whh(const float* __restrict__ Wf, const float* __restrict__ Wb,
                         float* __restrict__ WTf, float* __restrict__ WTb) {
    int idx = blockIdx.x * 256 + threadIdx.x;   // 0..393215
    if (idx >= 2 * H_ * G3_) return;
    int dir = idx / (H_ * G3_);
    int r = idx % (H_ * G3_);
    int k = r / G3_;
    int g = r % G3_;
    const float* W = dir ? Wb : Wf;
    float* O = dir ? WTb : WTf;
    O[r] = W[(size_t)g * H_ + k];
}

// cwT[(d*3+j)*256 + co] = conv_w[co][d][j]
__global__ void k_tr_cw(const float* __restrict__ cw, float* __restrict__ cwT) {
    int i = blockIdx.x * 256 + threadIdx.x;
    if (i >= CO_ * D_ * 3) return;
    int co = i & 255;
    int dj = i >> 8;                // d*3+j
    cwT[i] = cw[(size_t)co * (D_ * 3) + dj];
}

// ---------------- xg GEMM ----------------
// out[t][b][g] = sum_k sents[b][t][k]*Wih[g][k] + me[dir][mask[b][t]][g]
// M=16384 (bt), N=768, K=1024. Tile 64x64x16, 256 threads, 4x4 per thread.
__global__ __launch_bounds__(256) void k_gemm_xg(
        const float* __restrict__ sents, const float* __restrict__ Wf,
        const float* __restrict__ Wb, const float* __restrict__ me,
        const int* __restrict__ masks,
        float* __restrict__ xgf, float* __restrict__ xgb) {
    const int dir = blockIdx.z;
    const float* W = dir ? Wb : Wf;
    float* out = dir ? xgb : xgf;
    const float* meD = me + dir * (2 * G3_);
    const int bm = blockIdx.x * 64;
    const int bn = blockIdx.y * 64;
    const int tid = threadIdx.x;
    const int tx = tid & 15, ty = tid >> 4;
    __shared__ float As[64 * 17];
    __shared__ float Bs[16 * 68];
    float acc[4][4] = {};
    const int lm = tid >> 2;          // 0..63
    const int lk = (tid & 3) * 4;     // 0,4,8,12
    for (int k0 = 0; k0 < E_; k0 += 16) {
        const float* ap = sents + (size_t)(bm + lm) * E_ + k0 + lk;
        float4 a4 = *reinterpret_cast<const float4*>(ap);
        As[lm * 17 + lk + 0] = a4.x;
        As[lm * 17 + lk + 1] = a4.y;
        As[lm * 17 + lk + 2] = a4.z;
        As[lm * 17 + lk + 3] = a4.w;
        const float* wp = W + (size_t)(bn + lm) * IN_ + k0 + lk;
        #pragma unroll
        for (int j = 0; j < 4; ++j) Bs[(lk + j) * 68 + lm] = wp[j];
        __syncthreads();
        #pragma unroll
        for (int k = 0; k < 16; ++k) {
            float a_[4], b_[4];
            #pragma unroll
            for (int i = 0; i < 4; ++i) a_[i] = As[(ty * 4 + i) * 17 + k];
            #pragma unroll
            for (int j = 0; j < 4; ++j) b_[j] = Bs[k * 68 + tx * 4 + j];
            #pragma unroll
            for (int i = 0; i < 4; ++i)
                #pragma unroll
                for (int j = 0; j < 4; ++j) acc[i][j] += a_[i] * b_[j];
        }
        __syncthreads();
    }
    #pragma unroll
    for (int i = 0; i < 4; ++i) {
        int bt = bm + ty * 4 + i;
        int b = bt >> 7, t = bt & 127;
        int mk = masks[bt];
        const float* mp = meD + mk * G3_ + bn + tx * 4;
        float* op = out + ((size_t)(t * B_ + b)) * G3_ + bn + tx * 4;
        #pragma unroll
        for (int j = 0; j < 4; ++j) op[j] = acc[i][j] + mp[j];
    }
}

// ---------------- GRU scan ----------------
// One block: 4 batch rows, one direction, all 128 steps. 256 threads (one per hidden unit).
__global__ __launch_bounds__(256) void k_gru(
        const float* __restrict__ xgf, const float* __restrict__ xgb,
        const float* __restrict__ WTf, const float* __restrict__ WTb,
        const float* __restrict__ bhhf, const float* __restrict__ bhhb,
        const int* __restrict__ lens, float* __restrict__ ctx) {
    const int dir = blockIdx.y;
    const int b0 = blockIdx.x * 4;
    const int tid = threadIdx.x;
    const float* xg = dir ? xgb : xgf;
    const float* WT = dir ? WTb : WTf;
    const float* bhh = dir ? bhhb : bhhf;
    __shared__ float h_s[4][H_];
    #pragma unroll
    for (int r = 0; r < 4; ++r) h_s[r][tid] = 0.f;
    int len_[4];
    #pragma unroll
    for (int r = 0; r < 4; ++r) len_[r] = lens[b0 + r];
    const float bh0 = bhh[tid], bh1 = bhh[H_ + tid], bh2 = bhh[2 * H_ + tid];
    __syncthreads();
    for (int s = 0; s < T_; ++s) {
        const int t = dir ? (T_ - 1 - s) : s;
        float a0[4] = {0, 0, 0, 0}, a1[4] = {0, 0, 0, 0}, a2[4] = {0, 0, 0, 0};
        for (int k = 0; k < H_; ++k) {
            float w0 = WT[k * G3_ + tid];
            float w1 = WT[k * G3_ + H_ + tid];
            float w2 = WT[k * G3_ + 2 * H_ + tid];
            #pragma unroll
            for (int r = 0; r < 4; ++r) {
                float hv = h_s[r][k];
                a0[r] += w0 * hv;
                a1[r] += w1 * hv;
                a2[r] += w2 * hv;
            }
        }
        float hn[4];
        #pragma unroll
        for (int r = 0; r < 4; ++r) {
            const float* gg = xg + ((size_t)(t * B_ + b0 + r)) * G3_;
            float g0 = gg[tid], g1 = gg[H_ + tid], g2 = gg[2 * H_ + tid];
            float rg = 1.f / (1.f + expf(-(g0 + a0[r] + bh0)));
            float zg = 1.f / (1.f + expf(-(g1 + a1[r] + bh1)));
            float ng = tanhf(g2 + rg * (a2[r] + bh2));
            float ho = h_s[r][tid];
            float v = (1.f - zg) * ng + zg * ho;
            hn[r] = (t < len_[r]) ? v : ho;
        }
        __syncthreads();
        #pragma unroll
        for (int r = 0; r < 4; ++r) {
            h_s[r][tid] = hn[r];
            ctx[((size_t)((b0 + r) * T_ + t)) * D_ + dir * H_ + tid] = hn[r];
        }
        __syncthreads();
    }
}

// ---------------- conv1d (D->CO, k=3, pad=1) + ReLU ----------------
// block: one b, 16 t's; thread = co.
__global__ __launch_bounds__(256) void k_conv(
        const float* __restrict__ ctx, const float* __restrict__ cwT,
        const float* __restrict__ cb, float* __restrict__ ctx2) {
    const int b = blockIdx.y;
    const int t0 = blockIdx.x * 16;
    const int tid = threadIdx.x;
    __shared__ float s[18][D_];
    for (int i = tid; i < 18 * D_ / 4; i += 256) {
        int flat = i * 4;
        int row = flat >> 9;
        int col = flat & (D_ - 1);
        int t = t0 - 1 + row;
        float4 v = make_float4(0.f, 0.f, 0.f, 0.f);
        if (t >= 0 && t < T_)
            v = *reinterpret_cast<const float4*>(ctx + ((size_t)(b * T_ + t)) * D_ + col);
        *reinterpret_cast<float4*>(&s[row][col]) = v;
    }
    __syncthreads();
    float acc[16];
    const float bias = cb[tid];
    #pragma unroll
    for (int i = 0; i < 16; ++i) acc[i] = bias;
    for (int d = 0; d < D_; d += 4) {
        float vv[72];
        #pragma unroll
        for (int r = 0; r < 18; ++r) {
            float4 q = *reinterpret_cast<const float4*>(&s[r][d]);
            vv[r * 4 + 0] = q.x; vv[r * 4 + 1] = q.y;
            vv[r * 4 + 2] = q.z; vv[r * 4 + 3] = q.w;
        }
        #pragma unroll
        for (int sub = 0; sub < 4; ++sub) {
            float w0 = cwT[((d + sub) * 3 + 0) * CO_ + tid];
            float w1 = cwT[((d + sub) * 3 + 1) * CO_ + tid];
            float w2 = cwT[((d + sub) * 3 + 2) * CO_ + tid];
            #pragma unroll
            for (int ti = 0; ti < 16; ++ti) {
                acc[ti] += w0 * vv[(ti + 0) * 4 + sub];
                acc[ti] += w1 * vv[(ti + 1) * 4 + sub];
                acc[ti] += w2 * vv[(ti + 2) * 4 + sub];
            }
        }
    }
    #pragma unroll
    for (int ti = 0; ti < 16; ++ti) {
        ctx2[((size_t)(b * T_ + t0 + ti)) * CO_ + tid] = fmaxf(acc[ti], 0.f);
    }
}

// ---------------- feats + CRF + pooled head (one block per batch row) ----------------
__global__ __launch_bounds__(256) void k_head(
        const float* __restrict__ ctx2, const float* __restrict__ W_tri,
        const float* __restrict__ b_tri, const float* __restrict__ trans,
        const float* __restrict__ W_lab, const float* __restrict__ b_lab,
        const int* __restrict__ lens, const int* __restrict__ labels,
        float* __restrict__ loss_b, float* __restrict__ spsum_b) {
    const int b = blockIdx.x;
    const int tid = threadIdx.x;
    __shared__ float f_s[T_][4];
    __shared__ float al[T_][4];
    __shared__ float be[T_][4];
    __shared__ float sp_s[T_];
    __shared__ float sv_s[CO_];
    __shared__ float sred[3];
    __shared__ float s_spsum;
    const int len = lens[b];
    // feats[t][k]
    for (int idx = tid; idx < T_ * 4; idx += 256) {
        int t = idx >> 2, k = idx & 3;
        const float* row = ctx2 + ((size_t)(b * T_ + t)) * CO_;
        const float* w = W_tri + k * CO_;
        float acc = b_tri[k];
        for (int c = 0; c < CO_; ++c) acc += row[c] * w[c];
        f_s[t][k] = acc;
    }
    __syncthreads();
    if (tid == 0) {
        // forward scan
        float Tr[16];
        #pragma unroll
        for (int i = 0; i < 16; ++i) Tr[i] = trans[i];
        float a[4];
        #pragma unroll
        for (int k = 0; k < 4; ++k) { a[k] = f_s[0][k]; al[0][k] = a[k]; }
        for (int t = 1; t < T_; ++t) {
            float an[4];
            #pragma unroll
            for (int j = 0; j < 4; ++j) {
                float m = a[0] + Tr[0 * 4 + j];
                #pragma unroll
                for (int i = 1; i < 4; ++i) m = fmaxf(m, a[i] + Tr[i * 4 + j]);
                float sum = 0.f;
                #pragma unroll
                for (int i = 0; i < 4; ++i) sum += expf(a[i] + Tr[i * 4 + j] - m);
                an[j] = f_s[t][j] + m + logf(sum);
            }
            if (t < len) {
                #pragma unroll
                for (int k = 0; k < 4; ++k) a[k] = an[k];
            }
            #pragma unroll
            for (int k = 0; k < 4; ++k) al[t][k] = a[k];
        }
    } else if (tid == 64) {
        // backward scan
        float Tr[16];
        #pragma unroll
        for (int i = 0; i < 16; ++i) Tr[i] = trans[i];
        float bb[4] = {0, 0, 0, 0};
        #pragma unroll
        for (int k = 0; k < 4; ++k) be[T_ - 1][k] = 0.f;
        for (int t = T_ - 2; t >= 0; --t) {
            float bn[4];
            #pragma unroll
            for (int i = 0; i < 4; ++i) {
                float m = Tr[i * 4 + 0] + f_s[t + 1][0] + bb[0];
                #pragma unroll
                for (int j = 1; j < 4; ++j) m = fmaxf(m, Tr[i * 4 + j] + f_s[t + 1][j] + bb[j]);
                float sum = 0.f;
                #pragma unroll
                for (int j = 0; j < 4; ++j) sum += expf(Tr[i * 4 + j] + f_s[t + 1][j] + bb[j] - m);
                bn[i] = m + logf(sum);
            }
            if (t + 1 < len) {
                #pragma unroll
                for (int k = 0; k < 4; ++k) bb[k] = bn[k];
            }
            #pragma unroll
            for (int k = 0; k < 4; ++k) be[t][k] = bb[k];
        }
    }
    __syncthreads();
    if (tid < T_) {
        int t = tid;
        float s0 = al[t][0] + be[t][0];
        float s1 = al[t][1] + be[t][1];
        float s2 = al[t][2] + be[t][2];
        float s3 = al[t][3] + be[t][3];
        float m = fmaxf(fmaxf(s0, s1), fmaxf(s2, s3));
        float e0 = expf(s0 - m), e1 = expf(s1 - m), e2 = expf(s2 - m), e3 = expf(s3 - m);
        float p1 = e1 / (e0 + e1 + e2 + e3);
        sp_s[t] = (t < len) ? p1 : 0.f;
    }
    __syncthreads();
    if (tid == 0) {
        float s = 0.f;
        for (int t = 0; t < T_; ++t) s += sp_s[t];
        s_spsum = s;
    }
    __syncthreads();
    const float spsum = s_spsum;
    {
        float acc = 0.f;
        for (int t = 0; t < T_; ++t)
            acc += sp_s[t] * ctx2[((size_t)(b * T_ + t)) * CO_ + tid];
        sv_s[tid] = acc * 2.f / spsum;
    }
    __syncthreads();
    if (tid < 3) {
        float acc = b_lab[tid];
        const float* w = W_lab + tid * CO_;
        for (int c = 0; c < CO_; ++c) acc += sv_s[c] * w[c];
        sred[tid] = acc;
    }
    __syncthreads();
    if (tid == 0) {
        float m = fmaxf(sred[0], fmaxf(sred[1], sred[2]));
        float lse = m + logf(expf(sred[0] - m) + expf(sred[1] - m) + expf(sred[2] - m));
        loss_b[b] = lse - sred[labels[b]];
        spsum_b[b] = spsum;
    }
}

__global__ void k_final(const float* __restrict__ loss_b, const float* __restrict__ spsum_b,
                        const float* __restrict__ trans, float* __restrict__ out) {
    __shared__ float s1[128], s2[128];
    int tid = threadIdx.x;
    s1[tid] = loss_b[tid];
    s2[tid] = spsum_b[tid];
    __syncthreads();
    for (int off = 64; off > 0; off >>= 1) {
        if (tid < off) { s1[tid] += s1[tid + off]; s2[tid] += s2[tid + off]; }
        __syncthreads();
    }
    if (tid == 0) {
        float pena = fmaxf(trans[1 * 4 + 0] - trans[0 * 4 + 0], 0.f)
                   + fmaxf(trans[0 * 4 + 1] - trans[1 * 4 + 1], 0.f);
        out[0] = s1[0] / (float)B_;
        out[1] = 0.1f * pena + 0.1f * (s2[0] / (float)B_);
    }
}

// ---------------- launch ----------------
extern "C" void kernel_launch(void* const* d_in, const int* in_sizes, int n_in,
                              void* d_out, int out_size, void* d_ws, size_t ws_size,
                              hipStream_t stream) {
    const float* sents   = (const float*)d_in[0];
    const int*   masks   = (const int*)d_in[1];
    const int*   labels  = (const int*)d_in[2];
    const int*   lens    = (const int*)d_in[3];
    const float* mask_emb= (const float*)d_in[4];
    const float* Wih_f   = (const float*)d_in[5];
    const float* Whh_f   = (const float*)d_in[6];
    const float* bih_f   = (const float*)d_in[7];
    const float* bhh_f   = (const float*)d_in[8];
    const float* Wih_b   = (const float*)d_in[9];
    const float* Whh_b   = (const float*)d_in[10];
    const float* bih_b   = (const float*)d_in[11];
    const float* bhh_b   = (const float*)d_in[12];
    const float* conv_w  = (const float*)d_in[13];
    const float* conv_b  = (const float*)d_in[14];
    const float* W_tri   = (const float*)d_in[15];
    const float* b_tri   = (const float*)d_in[16];
    const float* trans   = (const float*)d_in[17];
    const float* W_lab   = (const float*)d_in[18];
    const float* b_lab   = (const float*)d_in[19];
    float* out = (float*)d_out;
    float* ws = (float*)d_ws;

    const size_t o_xgf  = 0;
    const size_t o_xgb  = o_xgf  + (size_t)B_ * T_ * G3_;   // 12582912
    const size_t o_ctx  = o_xgb  + (size_t)B_ * T_ * G3_;
    const size_t o_ctx2 = o_ctx  + (size_t)B_ * T_ * D_;
    const size_t o_wtf  = o_ctx2 + (size_t)B_ * T_ * CO_;
    const size_t o_wtb  = o_wtf  + (size_t)H_ * G3_;
    const size_t o_me   = o_wtb  + (size_t)H_ * G3_;
    const size_t o_cwt  = o_me   + 2 * 2 * G3_;
    const size_t o_lossb= o_cwt  + (size_t)D_ * 3 * CO_;
    const size_t o_spsum= o_lossb + B_;

    float* xgf  = ws + o_xgf;
    float* xgb  = ws + o_xgb;
    float* ctx  = ws + o_ctx;
    float* ctx2 = ws + o_ctx2;
    float* WTf  = ws + o_wtf;
    float* WTb  = ws + o_wtb;
    float* me   = ws + o_me;
    float* cwT  = ws + o_cwt;
    float* lossb = ws + o_lossb;
    float* spsumb = ws + o_spsum;

    k_prep_me<<<12, 256, 0, stream>>>(mask_emb, Wih_f, bih_f, Wih_b, bih_b, me);
    k_tr_whh<<<1536, 256, 0, stream>>>(Whh_f, Whh_b, WTf, WTb);
    k_tr_cw<<<1536, 256, 0, stream>>>(conv_w, cwT);
    k_gemm_xg<<<dim3(256, 12, 2), 256, 0, stream>>>(sents, Wih_f, Wih_b, me, masks, xgf, xgb);
    k_gru<<<dim3(32, 2), 256, 0, stream>>>(xgf, xgb, WTf, WTb, bhh_f, bhh_b, lens, ctx);
    k_conv<<<dim3(8, 128), 256, 0, stream>>>(ctx, cwT, conv_b, ctx2);
    k_head<<<128, 256, 0, stream>>>(ctx2, W_tri, b_tri, trans, W_lab, b_lab,
                                    lens, labels, lossb, spsumb);
    k_final<<<1, 128, 0, stream>>>(lossb, spsumb, trans, out);
}

// Round 2
// 1789.163 us; speedup vs baseline: 1.6751x; 1.6751x over previous
//
#include <hip/hip_runtime.h>
#include <hip/hip_bf16.h>
#include <math.h>

#define B_ 128
#define T_ 128
#define E_ 1024
#define IN_ 1074
#define H_ 256
#define G3_ 768
#define D_ 512
#define CO_ 256

typedef unsigned int uint_t;
typedef _Float16 v2h __attribute__((ext_vector_type(2)));

// ---------------- prep kernels ----------------

// me[dir][m][g] = bih[g] + sum_c mask_emb[m][c] * Wih[g][1024+c]
__global__ void k_prep_me(const float* __restrict__ mask_emb,
                          const float* __restrict__ Wf, const float* __restrict__ bf,
                          const float* __restrict__ Wb, const float* __restrict__ bb,
                          float* __restrict__ me) {
    int idx = blockIdx.x * 256 + threadIdx.x;   // 0..3071
    if (idx >= 2 * 2 * G3_) return;
    int dir = idx / (2 * G3_);
    int rem = idx % (2 * G3_);
    int m = rem / G3_;
    int g = rem % G3_;
    const float* W = dir ? Wb : Wf;
    const float* bi = dir ? bb : bf;
    float acc = bi[g];
    const float* wrow = W + (size_t)g * IN_ + E_;
    const float* e = mask_emb + m * 50;
    #pragma unroll 10
    for (int c = 0; c < 50; ++c) acc += e[c] * wrow[c];
    me[idx] = acc;
}

// wp[dir][kp][g] = packed f16 pair (Whh[g][2kp], Whh[g][2kp+1])
__global__ void k_prep_wh(const float* __restrict__ Wf, const float* __restrict__ Wb,
                          uint_t* __restrict__ wp) {
    int idx = blockIdx.x * 256 + threadIdx.x;   // 0..196607
    if (idx >= 2 * (H_ / 2) * G3_) return;
    int dir = idx / ((H_ / 2) * G3_);
    int r = idx % ((H_ / 2) * G3_);
    int kp = r / G3_;
    int g = r % G3_;
    const float* W = dir ? Wb : Wf;
    float w0 = W[(size_t)g * H_ + 2 * kp];
    float w1 = W[(size_t)g * H_ + 2 * kp + 1];
    uint_t u0 = (uint_t)__builtin_bit_cast(unsigned short, (_Float16)w0);
    uint_t u1 = (uint_t)__builtin_bit_cast(unsigned short, (_Float16)w1);
    wp[idx] = u0 | (u1 << 16);
}

// cwT[(d*3+j)*256 + co] = conv_w[co][d][j]
__global__ void k_tr_cw(const float* __restrict__ cw, float* __restrict__ cwT) {
    int i = blockIdx.x * 256 + threadIdx.x;
    if (i >= CO_ * D_ * 3) return;
    int co = i & 255;
    int dj = i >> 8;                // d*3+j
    cwT[i] = cw[(size_t)co * (D_ * 3) + dj];
}

// ---------------- xg GEMM ----------------
// out[t][b][g] = sum_k sents[b][t][k]*Wih[g][k] + me[dir][mask[b][t]][g]
// M=16384 (bt), N=768, K=1024. Tile 64x64x16, 256 threads, 4x4 per thread.
__global__ __launch_bounds__(256) void k_gemm_xg(
        const float* __restrict__ sents, const float* __restrict__ Wf,
        const float* __restrict__ Wb, const float* __restrict__ me,
        const int* __restrict__ masks,
        float* __restrict__ xgf, float* __restrict__ xgb) {
    const int dir = blockIdx.z;
    const float* W = dir ? Wb : Wf;
    float* out = dir ? xgb : xgf;
    const float* meD = me + dir * (2 * G3_);
    const int bm = blockIdx.x * 64;
    const int bn = blockIdx.y * 64;
    const int tid = threadIdx.x;
    const int tx = tid & 15, ty = tid >> 4;
    __shared__ float As[64 * 17];
    __shared__ float Bs[16 * 68];
    float acc[4][4] = {};
    const int lm = tid >> 2;          // 0..63
    const int lk = (tid & 3) * 4;     // 0,4,8,12
    for (int k0 = 0; k0 < E_; k0 += 16) {
        const float* ap = sents + (size_t)(bm + lm) * E_ + k0 + lk;
        float4 a4 = *reinterpret_cast<const float4*>(ap);
        As[lm * 17 + lk + 0] = a4.x;
        As[lm * 17 + lk + 1] = a4.y;
        As[lm * 17 + lk + 2] = a4.z;
        As[lm * 17 + lk + 3] = a4.w;
        const float* wp = W + (size_t)(bn + lm) * IN_ + k0 + lk;
        #pragma unroll
        for (int j = 0; j < 4; ++j) Bs[(lk + j) * 68 + lm] = wp[j];
        __syncthreads();
        #pragma unroll
        for (int k = 0; k < 16; ++k) {
            float a_[4], b_[4];
            #pragma unroll
            for (int i = 0; i < 4; ++i) a_[i] = As[(ty * 4 + i) * 17 + k];
            #pragma unroll
            for (int j = 0; j < 4; ++j) b_[j] = Bs[k * 68 + tx * 4 + j];
            #pragma unroll
            for (int i = 0; i < 4; ++i)
                #pragma unroll
                for (int j = 0; j < 4; ++j) acc[i][j] += a_[i] * b_[j];
        }
        __syncthreads();
    }
    #pragma unroll
    for (int i = 0; i < 4; ++i) {
        int bt = bm + ty * 4 + i;
        int b = bt >> 7, t = bt & 127;
        int mk = masks[bt];
        const float* mp = meD + mk * G3_ + bn + tx * 4;
        float* op = out + ((size_t)(t * B_ + b)) * G3_ + bn + tx * 4;
        #pragma unroll
        for (int j = 0; j < 4; ++j) op[j] = acc[i][j] + mp[j];
    }
}

// ---------------- GRU scan ----------------
// One block = one (batch row, direction). 256 threads, thread j owns hidden unit j.
// h state exact in f32 registers; cross-unit h exchanged as packed f16 pairs in LDS.
__device__ __forceinline__ float dot2(uint_t w, uint_t h, float acc) {
#if __has_builtin(__builtin_amdgcn_fdot2)
    return __builtin_amdgcn_fdot2(__builtin_bit_cast(v2h, w),
                                  __builtin_bit_cast(v2h, h), acc, false);
#else
    v2h a = __builtin_bit_cast(v2h, w), b = __builtin_bit_cast(v2h, h);
    return acc + (float)a[0] * (float)b[0] + (float)a[1] * (float)b[1];
#endif
}

__global__ __launch_bounds__(256) void k_gru(
        const float* __restrict__ xgf, const float* __restrict__ xgb,
        const uint_t* __restrict__ wp,
        const float* __restrict__ bhhf, const float* __restrict__ bhhb,
        const int* __restrict__ lens, float* __restrict__ ctx) {
    const int dir = blockIdx.y;
    const int b = blockIdx.x;
    const int j = threadIdx.x;
    const float* xg = dir ? xgb : xgf;
    const uint_t* wr = wp + (size_t)dir * ((H_ / 2) * G3_);
    const float* bhh = dir ? bhhb : bhhf;
    __shared__ uint_t h2s[2][128];
    if (j < 128) h2s[0][j] = 0u;
    const int len = lens[b];
    const float bh0 = bhh[j], bh1 = bhh[H_ + j], bh2 = bhh[2 * H_ + j];
    float hcur = 0.f;
    __syncthreads();
    for (int s = 0; s < T_; ++s) {
        const int t = dir ? (T_ - 1 - s) : s;
        const int cur = s & 1, nxt = cur ^ 1;
        const float* gg = xg + ((size_t)(t * B_ + b)) * G3_;
        float g0 = gg[j], g1 = gg[H_ + j], g2 = gg[2 * H_ + j];
        float a0 = 0.f, a1 = 0.f, a2 = 0.f;
        #pragma unroll 2
        for (int kp = 0; kp < H_ / 2; kp += 4) {
            uint4 hp = *reinterpret_cast<const uint4*>(&h2s[cur][kp]);
            const uint_t* wk = wr + (size_t)kp * G3_ + j;
            uint_t w00 = wk[0];
            uint_t w01 = wk[H_];
            uint_t w02 = wk[2 * H_];
            uint_t w10 = wk[G3_];
            uint_t w11 = wk[G3_ + H_];
            uint_t w12 = wk[G3_ + 2 * H_];
            uint_t w20 = wk[2 * G3_];
            uint_t w21 = wk[2 * G3_ + H_];
            uint_t w22 = wk[2 * G3_ + 2 * H_];
            uint_t w30 = wk[3 * G3_];
            uint_t w31 = wk[3 * G3_ + H_];
            uint_t w32 = wk[3 * G3_ + 2 * H_];
            a0 = dot2(w00, hp.x, a0); a1 = dot2(w01, hp.x, a1); a2 = dot2(w02, hp.x, a2);
            a0 = dot2(w10, hp.y, a0); a1 = dot2(w11, hp.y, a1); a2 = dot2(w12, hp.y, a2);
            a0 = dot2(w20, hp.z, a0); a1 = dot2(w21, hp.z, a1); a2 = dot2(w22, hp.z, a2);
            a0 = dot2(w30, hp.w, a0); a1 = dot2(w31, hp.w, a1); a2 = dot2(w32, hp.w, a2);
        }
        float rg = 1.f / (1.f + expf(-(g0 + a0 + bh0)));
        float zg = 1.f / (1.f + expf(-(g1 + a1 + bh1)));
        float ng = tanhf(g2 + rg * (a2 + bh2));
        float v = (1.f - zg) * ng + zg * hcur;
        hcur = (t < len) ? v : hcur;
        ctx[((size_t)(b * T_ + t)) * D_ + dir * H_ + j] = hcur;
        ((_Float16*)&h2s[nxt][0])[j] = (_Float16)hcur;
        __syncthreads();
    }
}

// ---------------- conv1d (D->CO, k=3, pad=1) + ReLU ----------------
// block: one b, 16 t's; thread = co.
__global__ __launch_bounds__(256) void k_conv(
        const float* __restrict__ ctx, const float* __restrict__ cwT,
        const float* __restrict__ cb, float* __restrict__ ctx2) {
    const int b = blockIdx.y;
    const int t0 = blockIdx.x * 16;
    const int tid = threadIdx.x;
    __shared__ float s[18][D_];
    for (int i = tid; i < 18 * D_ / 4; i += 256) {
        int flat = i * 4;
        int row = flat >> 9;
        int col = flat & (D_ - 1);
        int t = t0 - 1 + row;
        float4 v = make_float4(0.f, 0.f, 0.f, 0.f);
        if (t >= 0 && t < T_)
            v = *reinterpret_cast<const float4*>(ctx + ((size_t)(b * T_ + t)) * D_ + col);
        *reinterpret_cast<float4*>(&s[row][col]) = v;
    }
    __syncthreads();
    float acc[16];
    const float bias = cb[tid];
    #pragma unroll
    for (int i = 0; i < 16; ++i) acc[i] = bias;
    for (int d = 0; d < D_; d += 4) {
        float vv[72];
        #pragma unroll
        for (int r = 0; r < 18; ++r) {
            float4 q = *reinterpret_cast<const float4*>(&s[r][d]);
            vv[r * 4 + 0] = q.x; vv[r * 4 + 1] = q.y;
            vv[r * 4 + 2] = q.z; vv[r * 4 + 3] = q.w;
        }
        #pragma unroll
        for (int sub = 0; sub < 4; ++sub) {
            float w0 = cwT[((d + sub) * 3 + 0) * CO_ + tid];
            float w1 = cwT[((d + sub) * 3 + 1) * CO_ + tid];
            float w2 = cwT[((d + sub) * 3 + 2) * CO_ + tid];
            #pragma unroll
            for (int ti = 0; ti < 16; ++ti) {
                acc[ti] += w0 * vv[(ti + 0) * 4 + sub];
                acc[ti] += w1 * vv[(ti + 1) * 4 + sub];
                acc[ti] += w2 * vv[(ti + 2) * 4 + sub];
            }
        }
    }
    #pragma unroll
    for (int ti = 0; ti < 16; ++ti) {
        ctx2[((size_t)(b * T_ + t0 + ti)) * CO_ + tid] = fmaxf(acc[ti], 0.f);
    }
}

// ---------------- feats + CRF + pooled head (one block per batch row) ----------------
__global__ __launch_bounds__(256) void k_head(
        const float* __restrict__ ctx2, const float* __restrict__ W_tri,
        const float* __restrict__ b_tri, const float* __restrict__ trans,
        const float* __restrict__ W_lab, const float* __restrict__ b_lab,
        const int* __restrict__ lens, const int* __restrict__ labels,
        float* __restrict__ loss_b, float* __restrict__ spsum_b) {
    const int b = blockIdx.x;
    const int tid = threadIdx.x;
    __shared__ float f_s[T_][4];
    __shared__ float al[T_][4];
    __shared__ float be[T_][4];
    __shared__ float sp_s[T_];
    __shared__ float sv_s[CO_];
    __shared__ float sred[3];
    __shared__ float s_spsum;
    const int len = lens[b];
    // feats[t][k]
    for (int idx = tid; idx < T_ * 4; idx += 256) {
        int t = idx >> 2, k = idx & 3;
        const float* row = ctx2 + ((size_t)(b * T_ + t)) * CO_;
        const float* w = W_tri + k * CO_;
        float acc = b_tri[k];
        for (int c = 0; c < CO_; ++c) acc += row[c] * w[c];
        f_s[t][k] = acc;
    }
    __syncthreads();
    if (tid == 0) {
        // forward scan
        float Tr[16];
        #pragma unroll
        for (int i = 0; i < 16; ++i) Tr[i] = trans[i];
        float a[4];
        #pragma unroll
        for (int k = 0; k < 4; ++k) { a[k] = f_s[0][k]; al[0][k] = a[k]; }
        for (int t = 1; t < T_; ++t) {
            float an[4];
            #pragma unroll
            for (int j = 0; j < 4; ++j) {
                float m = a[0] + Tr[0 * 4 + j];
                #pragma unroll
                for (int i = 1; i < 4; ++i) m = fmaxf(m, a[i] + Tr[i * 4 + j]);
                float sum = 0.f;
                #pragma unroll
                for (int i = 0; i < 4; ++i) sum += expf(a[i] + Tr[i * 4 + j] - m);
                an[j] = f_s[t][j] + m + logf(sum);
            }
            if (t < len) {
                #pragma unroll
                for (int k = 0; k < 4; ++k) a[k] = an[k];
            }
            #pragma unroll
            for (int k = 0; k < 4; ++k) al[t][k] = a[k];
        }
    } else if (tid == 64) {
        // backward scan
        float Tr[16];
        #pragma unroll
        for (int i = 0; i < 16; ++i) Tr[i] = trans[i];
        float bb[4] = {0, 0, 0, 0};
        #pragma unroll
        for (int k = 0; k < 4; ++k) be[T_ - 1][k] = 0.f;
        for (int t = T_ - 2; t >= 0; --t) {
            float bn[4];
            #pragma unroll
            for (int i = 0; i < 4; ++i) {
                float m = Tr[i * 4 + 0] + f_s[t + 1][0] + bb[0];
                #pragma unroll
                for (int j = 1; j < 4; ++j) m = fmaxf(m, Tr[i * 4 + j] + f_s[t + 1][j] + bb[j]);
                float sum = 0.f;
                #pragma unroll
                for (int j = 0; j < 4; ++j) sum += expf(Tr[i * 4 + j] + f_s[t + 1][j] + bb[j] - m);
                bn[i] = m + logf(sum);
            }
            if (t + 1 < len) {
                #pragma unroll
                for (int k = 0; k < 4; ++k) bb[k] = bn[k];
            }
            #pragma unroll
            for (int k = 0; k < 4; ++k) be[t][k] = bb[k];
        }
    }
    __syncthreads();
    if (tid < T_) {
        int t = tid;
        float s0 = al[t][0] + be[t][0];
        float s1 = al[t][1] + be[t][1];
        float s2 = al[t][2] + be[t][2];
        float s3 = al[t][3] + be[t][3];
        float m = fmaxf(fmaxf(s0, s1), fmaxf(s2, s3));
        float e0 = expf(s0 - m), e1 = expf(s1 - m), e2 = expf(s2 - m), e3 = expf(s3 - m);
        float p1 = e1 / (e0 + e1 + e2 + e3);
        sp_s[t] = (t < len) ? p1 : 0.f;
    }
    __syncthreads();
    if (tid == 0) {
        float s = 0.f;
        for (int t = 0; t < T_; ++t) s += sp_s[t];
        s_spsum = s;
    }
    __syncthreads();
    const float spsum = s_spsum;
    {
        float acc = 0.f;
        for (int t = 0; t < T_; ++t)
            acc += sp_s[t] * ctx2[((size_t)(b * T_ + t)) * CO_ + tid];
        sv_s[tid] = acc * 2.f / spsum;
    }
    __syncthreads();
    if (tid < 3) {
        float acc = b_lab[tid];
        const float* w = W_lab + tid * CO_;
        for (int c = 0; c < CO_; ++c) acc += sv_s[c] * w[c];
        sred[tid] = acc;
    }
    __syncthreads();
    if (tid == 0) {
        float m = fmaxf(sred[0], fmaxf(sred[1], sred[2]));
        float lse = m + logf(expf(sred[0] - m) + expf(sred[1] - m) + expf(sred[2] - m));
        loss_b[b] = lse - sred[labels[b]];
        spsum_b[b] = spsum;
    }
}

__global__ void k_final(const float* __restrict__ loss_b, const float* __restrict__ spsum_b,
                        const float* __restrict__ trans, float* __restrict__ out) {
    __shared__ float s1[128], s2[128];
    int tid = threadIdx.x;
    s1[tid] = loss_b[tid];
    s2[tid] = spsum_b[tid];
    __syncthreads();
    for (int off = 64; off > 0; off >>= 1) {
        if (tid < off) { s1[tid] += s1[tid + off]; s2[tid] += s2[tid + off]; }
        __syncthreads();
    }
    if (tid == 0) {
        float pena = fmaxf(trans[1 * 4 + 0] - trans[0 * 4 + 0], 0.f)
                   + fmaxf(trans[0 * 4 + 1] - trans[1 * 4 + 1], 0.f);
        out[0] = s1[0] / (float)B_;
        out[1] = 0.1f * pena + 0.1f * (s2[0] / (float)B_);
    }
}

// ---------------- launch ----------------
extern "C" void kernel_launch(void* const* d_in, const int* in_sizes, int n_in,
                              void* d_out, int out_size, void* d_ws, size_t ws_size,
                              hipStream_t stream) {
    const float* sents   = (const float*)d_in[0];
    const int*   masks   = (const int*)d_in[1];
    const int*   labels  = (const int*)d_in[2];
    const int*   lens    = (const int*)d_in[3];
    const float* mask_emb= (const float*)d_in[4];
    const float* Wih_f   = (const float*)d_in[5];
    const float* Whh_f   = (const float*)d_in[6];
    const float* bih_f   = (const float*)d_in[7];
    const float* bhh_f   = (const float*)d_in[8];
    const float* Wih_b   = (const float*)d_in[9];
    const float* Whh_b   = (const float*)d_in[10];
    const float* bih_b   = (const float*)d_in[11];
    const float* bhh_b   = (const float*)d_in[12];
    const float* conv_w  = (const float*)d_in[13];
    const float* conv_b  = (const float*)d_in[14];
    const float* W_tri   = (const float*)d_in[15];
    const float* b_tri   = (const float*)d_in[16];
    const float* trans   = (const float*)d_in[17];
    const float* W_lab   = (const float*)d_in[18];
    const float* b_lab   = (const float*)d_in[19];
    float* out = (float*)d_out;
    float* ws = (float*)d_ws;

    const size_t o_xgf  = 0;
    const size_t o_xgb  = o_xgf  + (size_t)B_ * T_ * G3_;   // 12582912
    const size_t o_ctx  = o_xgb  + (size_t)B_ * T_ * G3_;
    const size_t o_ctx2 = o_ctx  + (size_t)B_ * T_ * D_;
    const size_t o_wp   = o_ctx2 + (size_t)B_ * T_ * CO_;   // uints: 2*128*768
    const size_t o_me   = o_wp   + (size_t)2 * (H_ / 2) * G3_;
    const size_t o_cwt  = o_me   + 2 * 2 * G3_;
    const size_t o_lossb= o_cwt  + (size_t)D_ * 3 * CO_;
    const size_t o_spsum= o_lossb + B_;

    float* xgf  = ws + o_xgf;
    float* xgb  = ws + o_xgb;
    float* ctx  = ws + o_ctx;
    float* ctx2 = ws + o_ctx2;
    uint_t* wp  = (uint_t*)(ws + o_wp);
    float* me   = ws + o_me;
    float* cwT  = ws + o_cwt;
    float* lossb = ws + o_lossb;
    float* spsumb = ws + o_spsum;

    k_prep_me<<<12, 256, 0, stream>>>(mask_emb, Wih_f, bih_f, Wih_b, bih_b, me);
    k_prep_wh<<<768, 256, 0, stream>>>(Whh_f, Whh_b, wp);
    k_tr_cw<<<1536, 256, 0, stream>>>(conv_w, cwT);
    k_gemm_xg<<<dim3(256, 12, 2), 256, 0, stream>>>(sents, Wih_f, Wih_b, me, masks, xgf, xgb);
    k_gru<<<dim3(B_, 2), 256, 0, stream>>>(xgf, xgb, wp, bhh_f, bhh_b, lens, ctx);
    k_conv<<<dim3(8, 128), 256, 0, stream>>>(ctx, cwT, conv_b, ctx2);
    k_head<<<128, 256, 0, stream>>>(ctx2, W_tri, b_tri, trans, W_lab, b_lab,
                                    lens, labels, lossb, spsumb);
    k_final<<<1, 128, 0, stream>>>(lossb, spsumb, trans, out);
}

// Round 3
// 1185.695 us; speedup vs baseline: 2.5276x; 1.5090x over previous
//
#include <hip/hip_runtime.h>
#include <hip/hip_bf16.h>
#include <math.h>

#define B_ 128
#define T_ 128
#define E_ 1024
#define IN_ 1074
#define H_ 256
#define G3_ 768
#define D_ 512
#define CO_ 256

typedef unsigned int uint_t;
typedef _Float16 v2h __attribute__((ext_vector_type(2)));
typedef _Float16 f16x8 __attribute__((ext_vector_type(8)));
typedef float f32x4 __attribute__((ext_vector_type(4)));

// ---------------- prep kernels ----------------

// me[dir][m][g] = bih[g] + sum_c mask_emb[m][c] * Wih[g][1024+c]
__global__ void k_prep_me(const float* __restrict__ mask_emb,
                          const float* __restrict__ Wf, const float* __restrict__ bf,
                          const float* __restrict__ Wb, const float* __restrict__ bb,
                          float* __restrict__ me) {
    int idx = blockIdx.x * 256 + threadIdx.x;   // 0..3071
    if (idx >= 2 * 2 * G3_) return;
    int dir = idx / (2 * G3_);
    int rem = idx % (2 * G3_);
    int m = rem / G3_;
    int g = rem % G3_;
    const float* W = dir ? Wb : Wf;
    const float* bi = dir ? bb : bf;
    float acc = bi[g];
    const float* wrow = W + (size_t)g * IN_ + E_;
    const float* e = mask_emb + m * 50;
    #pragma unroll 10
    for (int c = 0; c < 50; ++c) acc += e[c] * wrow[c];
    me[idx] = acc;
}

// wp[dir][kp][g] = packed f16 pair (Whh[g][2kp], Whh[g][2kp+1])
__global__ void k_prep_wh(const float* __restrict__ Wf, const float* __restrict__ Wb,
                          uint_t* __restrict__ wp) {
    int idx = blockIdx.x * 256 + threadIdx.x;   // 0..196607
    if (idx >= 2 * (H_ / 2) * G3_) return;
    int dir = idx / ((H_ / 2) * G3_);
    int r = idx % ((H_ / 2) * G3_);
    int kp = r / G3_;
    int g = r % G3_;
    const float* W = dir ? Wb : Wf;
    float w0 = W[(size_t)g * H_ + 2 * kp];
    float w1 = W[(size_t)g * H_ + 2 * kp + 1];
    uint_t u0 = (uint_t)__builtin_bit_cast(unsigned short, (_Float16)w0);
    uint_t u1 = (uint_t)__builtin_bit_cast(unsigned short, (_Float16)w1);
    wp[idx] = u0 | (u1 << 16);
}

// cwT[(d*3+j)*256 + co] = conv_w[co][d][j]
__global__ void k_tr_cw(const float* __restrict__ cw, float* __restrict__ cwT) {
    int i = blockIdx.x * 256 + threadIdx.x;
    if (i >= CO_ * D_ * 3) return;
    int co = i & 255;
    int dj = i >> 8;                // d*3+j
    cwT[i] = cw[(size_t)co * (D_ * 3) + dj];
}

__device__ __forceinline__ uint_t pk2(float a, float b) {
    uint_t u0 = (uint_t)__builtin_bit_cast(unsigned short, (_Float16)a);
    uint_t u1 = (uint_t)__builtin_bit_cast(unsigned short, (_Float16)b);
    return u0 | (u1 << 16);
}

// sents f32 -> f16 (packed). 16,777,216 elems, 8 per thread.
__global__ __launch_bounds__(256) void k_cvt_sents(const float* __restrict__ in,
                                                   uint_t* __restrict__ out) {
    int i = blockIdx.x * 256 + threadIdx.x;    // 0..2097151
    float4 a = reinterpret_cast<const float4*>(in)[i * 2];
    float4 b = reinterpret_cast<const float4*>(in)[i * 2 + 1];
    uint4 o;
    o.x = pk2(a.x, a.y); o.y = pk2(a.z, a.w);
    o.z = pk2(b.x, b.y); o.w = pk2(b.z, b.w);
    reinterpret_cast<uint4*>(out)[i] = o;
}

// W16[n][k] = f16(Wih_dir[g][k]), n = dir*768+g, k<1024 (row stride IN_=1074)
__global__ __launch_bounds__(256) void k_cvt_w(const float* __restrict__ Wf,
                                               const float* __restrict__ Wb,
                                               uint_t* __restrict__ out) {
    int i = blockIdx.x * 256 + threadIdx.x;    // 0..196607 (1536*128)
    if (i >= 1536 * 128) return;
    int n = i >> 7, kq = i & 127;
    int dir = n >= G3_;
    int g = n - dir * G3_;
    const float* src = (dir ? Wb : Wf) + (size_t)g * IN_ + kq * 8;
    float2 a = reinterpret_cast<const float2*>(src)[0];
    float2 b = reinterpret_cast<const float2*>(src)[1];
    float2 c = reinterpret_cast<const float2*>(src)[2];
    float2 d = reinterpret_cast<const float2*>(src)[3];
    uint4 o;
    o.x = pk2(a.x, a.y); o.y = pk2(b.x, b.y);
    o.z = pk2(c.x, c.y); o.w = pk2(d.x, d.y);
    reinterpret_cast<uint4*>(out)[i] = o;
}

// ---------------- MFMA xg GEMM ----------------
// C[bt][n] = sum_k A16[bt][k] * W16[n][k]; n<768 -> xgf, else xgb; + me[dir][mask][g]
// M=16384, N=1536, K=1024. 128x128 tile, BK=32, 4 waves (2x2), 4x4 16x16x32 frags.

__device__ __forceinline__ void gload16(const void* g, void* l) {
    __builtin_amdgcn_global_load_lds(
        (const __attribute__((address_space(1))) void*)g,
        (__attribute__((address_space(3))) void*)l, 16, 0, 0);
}

__global__ __launch_bounds__(256) void k_gemm_mfma(
        const _Float16* __restrict__ A16, const _Float16* __restrict__ W16,
        const float* __restrict__ me, const int* __restrict__ masks,
        float* __restrict__ xgf, float* __restrict__ xgb) {
    __shared__ _Float16 As[4096];
    __shared__ _Float16 Bs[4096];
    const int bid = blockIdx.x;
    const int logical = (bid & 7) * 192 + (bid >> 3);   // XCD-contiguous chunks
    const int mt = logical / 12, nt = logical % 12;
    const int bm = mt * 128, bn = nt * 128;
    const int tid = threadIdx.x;
    const int w = tid >> 6, lane = tid & 63;
    const int wr = w >> 1, wc = w & 1;

    // staging: fragment-linear LDS. call r in {0,1}: subtile st=r*4+w,
    // lane -> row = st*16 + (lane&15), kbyte = (lane>>4)*16
    const int rl = lane & 15;
    const int kb = (lane >> 4) * 16;
    const int st0 = w, st1 = 4 + w;
    const char* gA0 = (const char*)A16 + (size_t)(bm + st0 * 16 + rl) * 2048 + kb;
    const char* gA1 = (const char*)A16 + (size_t)(bm + st1 * 16 + rl) * 2048 + kb;
    const char* gB0 = (const char*)W16 + (size_t)(bn + st0 * 16 + rl) * 2048 + kb;
    const char* gB1 = (const char*)W16 + (size_t)(bn + st1 * 16 + rl) * 2048 + kb;
    char* lA0 = (char*)As + w * 1024;
    char* lA1 = (char*)As + 4096 + w * 1024 - 0;  // subtiles 4..7 start at byte 4096
    char* lB0 = (char*)Bs + w * 1024;
    char* lB1 = (char*)Bs + 4096 + w * 1024 - 0;
    // NOTE: As is 4096 f16 = 8192 bytes; byte offsets 0..8191.

    f32x4 acc[4][4];
    #pragma unroll
    for (int m = 0; m < 4; ++m)
        #pragma unroll
        for (int n = 0; n < 4; ++n)
            acc[m][n] = (f32x4){0.f, 0.f, 0.f, 0.f};

    for (int kB = 0; kB < 2048; kB += 64) {   // 32 f16 per step, byte-indexed
        gload16(gA0 + kB, lA0);
        gload16(gA1 + kB, lA1);
        gload16(gB0 + kB, lB0);
        gload16(gB1 + kB, lB1);
        __syncthreads();
        f16x8 af[4], bf[4];
        #pragma unroll
        for (int m = 0; m < 4; ++m)
            af[m] = *reinterpret_cast<const f16x8*>(
                (const char*)As + (wr * 4 + m) * 1024 + lane * 16);
        #pragma unroll
        for (int n = 0; n < 4; ++n)
            bf[n] = *reinterpret_cast<const f16x8*>(
                (const char*)Bs + (wc * 4 + n) * 1024 + lane * 16);
        #pragma unroll
        for (int m = 0; m < 4; ++m)
            #pragma unroll
            for (int n = 0; n < 4; ++n)
                acc[m][n] = __builtin_amdgcn_mfma_f32_16x16x32_f16(
                    af[m], bf[n], acc[m][n], 0, 0, 0);
        __syncthreads();
    }

    const int qr = (lane >> 4) * 4;
    const int cc = lane & 15;
    #pragma unroll
    for (int m = 0; m < 4; ++m) {
        #pragma unroll
        for (int q = 0; q < 4; ++q) {
            const int bt = bm + wr * 64 + m * 16 + qr + q;
            const int mk = masks[bt];
            const int b = bt >> 7, t = bt & 127;
            #pragma unroll
            for (int n = 0; n < 4; ++n) {
                const int col = bn + wc * 64 + n * 16 + cc;
                const int dir = col >= G3_;
                const int g = col - dir * G3_;
                float v = acc[m][n][q] + me[dir * (2 * G3_) + mk * G3_ + g];
                float* dst = (dir ? xgb : xgf) + ((size_t)(t * B_ + b)) * G3_ + g;
                *dst = v;
            }
        }
    }
}

// ---------------- GRU scan ----------------
__device__ __forceinline__ float dot2(uint_t w, uint_t h, float acc) {
#if __has_builtin(__builtin_amdgcn_fdot2)
    return __builtin_amdgcn_fdot2(__builtin_bit_cast(v2h, w),
                                  __builtin_bit_cast(v2h, h), acc, false);
#else
    v2h a = __builtin_bit_cast(v2h, w), b = __builtin_bit_cast(v2h, h);
    return acc + (float)a[0] * (float)b[0] + (float)a[1] * (float)b[1];
#endif
}

__global__ __launch_bounds__(256) void k_gru(
        const float* __restrict__ xgf, const float* __restrict__ xgb,
        const uint_t* __restrict__ wp,
        const float* __restrict__ bhhf, const float* __restrict__ bhhb,
        const int* __restrict__ lens, float* __restrict__ ctx) {
    const int dir = blockIdx.y;
    const int b = blockIdx.x;
    const int j = threadIdx.x;
    const float* xg = dir ? xgb : xgf;
    const uint_t* wr = wp + (size_t)dir * ((H_ / 2) * G3_);
    const float* bhh = dir ? bhhb : bhhf;
    __shared__ uint_t h2s[2][128];
    if (j < 128) h2s[0][j] = 0u;
    const int len = lens[b];
    const float bh0 = bhh[j], bh1 = bhh[H_ + j], bh2 = bhh[2 * H_ + j];
    float hcur = 0.f;
    __syncthreads();
    for (int s = 0; s < T_; ++s) {
        const int t = dir ? (T_ - 1 - s) : s;
        const int cur = s & 1, nxt = cur ^ 1;
        const float* gg = xg + ((size_t)(t * B_ + b)) * G3_;
        float g0 = gg[j], g1 = gg[H_ + j], g2 = gg[2 * H_ + j];
        float a0 = 0.f, a1 = 0.f, a2 = 0.f;
        #pragma unroll 2
        for (int kp = 0; kp < H_ / 2; kp += 4) {
            uint4 hp = *reinterpret_cast<const uint4*>(&h2s[cur][kp]);
            const uint_t* wk = wr + (size_t)kp * G3_ + j;
            uint_t w00 = wk[0];
            uint_t w01 = wk[H_];
            uint_t w02 = wk[2 * H_];
            uint_t w10 = wk[G3_];
            uint_t w11 = wk[G3_ + H_];
            uint_t w12 = wk[G3_ + 2 * H_];
            uint_t w20 = wk[2 * G3_];
            uint_t w21 = wk[2 * G3_ + H_];
            uint_t w22 = wk[2 * G3_ + 2 * H_];
            uint_t w30 = wk[3 * G3_];
            uint_t w31 = wk[3 * G3_ + H_];
            uint_t w32 = wk[3 * G3_ + 2 * H_];
            a0 = dot2(w00, hp.x, a0); a1 = dot2(w01, hp.x, a1); a2 = dot2(w02, hp.x, a2);
            a0 = dot2(w10, hp.y, a0); a1 = dot2(w11, hp.y, a1); a2 = dot2(w12, hp.y, a2);
            a0 = dot2(w20, hp.z, a0); a1 = dot2(w21, hp.z, a1); a2 = dot2(w22, hp.z, a2);
            a0 = dot2(w30, hp.w, a0); a1 = dot2(w31, hp.w, a1); a2 = dot2(w32, hp.w, a2);
        }
        float rg = 1.f / (1.f + expf(-(g0 + a0 + bh0)));
        float zg = 1.f / (1.f + expf(-(g1 + a1 + bh1)));
        float ng = tanhf(g2 + rg * (a2 + bh2));
        float v = (1.f - zg) * ng + zg * hcur;
        hcur = (t < len) ? v : hcur;
        ctx[((size_t)(b * T_ + t)) * D_ + dir * H_ + j] = hcur;
        ((_Float16*)&h2s[nxt][0])[j] = (_Float16)hcur;
        __syncthreads();
    }
}

// ---------------- conv1d (D->CO, k=3, pad=1) + ReLU ----------------
__global__ __launch_bounds__(256) void k_conv(
        const float* __restrict__ ctx, const float* __restrict__ cwT,
        const float* __restrict__ cb, float* __restrict__ ctx2) {
    const int b = blockIdx.y;
    const int t0 = blockIdx.x * 16;
    const int tid = threadIdx.x;
    __shared__ float s[18][D_];
    for (int i = tid; i < 18 * D_ / 4; i += 256) {
        int flat = i * 4;
        int row = flat >> 9;
        int col = flat & (D_ - 1);
        int t = t0 - 1 + row;
        float4 v = make_float4(0.f, 0.f, 0.f, 0.f);
        if (t >= 0 && t < T_)
            v = *reinterpret_cast<const float4*>(ctx + ((size_t)(b * T_ + t)) * D_ + col);
        *reinterpret_cast<float4*>(&s[row][col]) = v;
    }
    __syncthreads();
    float acc[16];
    const float bias = cb[tid];
    #pragma unroll
    for (int i = 0; i < 16; ++i) acc[i] = bias;
    for (int d = 0; d < D_; d += 4) {
        float vv[72];
        #pragma unroll
        for (int r = 0; r < 18; ++r) {
            float4 q = *reinterpret_cast<const float4*>(&s[r][d]);
            vv[r * 4 + 0] = q.x; vv[r * 4 + 1] = q.y;
            vv[r * 4 + 2] = q.z; vv[r * 4 + 3] = q.w;
        }
        #pragma unroll
        for (int sub = 0; sub < 4; ++sub) {
            float w0 = cwT[((d + sub) * 3 + 0) * CO_ + tid];
            float w1 = cwT[((d + sub) * 3 + 1) * CO_ + tid];
            float w2 = cwT[((d + sub) * 3 + 2) * CO_ + tid];
            #pragma unroll
            for (int ti = 0; ti < 16; ++ti) {
                acc[ti] += w0 * vv[(ti + 0) * 4 + sub];
                acc[ti] += w1 * vv[(ti + 1) * 4 + sub];
                acc[ti] += w2 * vv[(ti + 2) * 4 + sub];
            }
        }
    }
    #pragma unroll
    for (int ti = 0; ti < 16; ++ti) {
        ctx2[((size_t)(b * T_ + t0 + ti)) * CO_ + tid] = fmaxf(acc[ti], 0.f);
    }
}

// ---------------- feats + CRF + pooled head ----------------
__global__ __launch_bounds__(256) void k_head(
        const float* __restrict__ ctx2, const float* __restrict__ W_tri,
        const float* __restrict__ b_tri, const float* __restrict__ trans,
        const float* __restrict__ W_lab, const float* __restrict__ b_lab,
        const int* __restrict__ lens, const int* __restrict__ labels,
        float* __restrict__ loss_b, float* __restrict__ spsum_b) {
    const int b = blockIdx.x;
    const int tid = threadIdx.x;
    __shared__ float f_s[T_][4];
    __shared__ float al[T_][4];
    __shared__ float be[T_][4];
    __shared__ float sp_s[T_];
    __shared__ float sv_s[CO_];
    __shared__ float sred[3];
    __shared__ float s_spsum;
    const int len = lens[b];
    for (int idx = tid; idx < T_ * 4; idx += 256) {
        int t = idx >> 2, k = idx & 3;
        const float* row = ctx2 + ((size_t)(b * T_ + t)) * CO_;
        const float* w = W_tri + k * CO_;
        float acc = b_tri[k];
        for (int c = 0; c < CO_; ++c) acc += row[c] * w[c];
        f_s[t][k] = acc;
    }
    __syncthreads();
    if (tid == 0) {
        float Tr[16];
        #pragma unroll
        for (int i = 0; i < 16; ++i) Tr[i] = trans[i];
        float a[4];
        #pragma unroll
        for (int k = 0; k < 4; ++k) { a[k] = f_s[0][k]; al[0][k] = a[k]; }
        for (int t = 1; t < T_; ++t) {
            float an[4];
            #pragma unroll
            for (int j = 0; j < 4; ++j) {
                float m = a[0] + Tr[0 * 4 + j];
                #pragma unroll
                for (int i = 1; i < 4; ++i) m = fmaxf(m, a[i] + Tr[i * 4 + j]);
                float sum = 0.f;
                #pragma unroll
                for (int i = 0; i < 4; ++i) sum += expf(a[i] + Tr[i * 4 + j] - m);
                an[j] = f_s[t][j] + m + logf(sum);
            }
            if (t < len) {
                #pragma unroll
                for (int k = 0; k < 4; ++k) a[k] = an[k];
            }
            #pragma unroll
            for (int k = 0; k < 4; ++k) al[t][k] = a[k];
        }
    } else if (tid == 64) {
        float Tr[16];
        #pragma unroll
        for (int i = 0; i < 16; ++i) Tr[i] = trans[i];
        float bb[4] = {0, 0, 0, 0};
        #pragma unroll
        for (int k = 0; k < 4; ++k) be[T_ - 1][k] = 0.f;
        for (int t = T_ - 2; t >= 0; --t) {
            float bn[4];
            #pragma unroll
            for (int i = 0; i < 4; ++i) {
                float m = Tr[i * 4 + 0] + f_s[t + 1][0] + bb[0];
                #pragma unroll
                for (int j = 1; j < 4; ++j) m = fmaxf(m, Tr[i * 4 + j] + f_s[t + 1][j] + bb[j]);
                float sum = 0.f;
                #pragma unroll
                for (int j = 0; j < 4; ++j) sum += expf(Tr[i * 4 + j] + f_s[t + 1][j] + bb[j] - m);
                bn[i] = m + logf(sum);
            }
            if (t + 1 < len) {
                #pragma unroll
                for (int k = 0; k < 4; ++k) bb[k] = bn[k];
            }
            #pragma unroll
            for (int k = 0; k < 4; ++k) be[t][k] = bb[k];
        }
    }
    __syncthreads();
    if (tid < T_) {
        int t = tid;
        float s0 = al[t][0] + be[t][0];
        float s1 = al[t][1] + be[t][1];
        float s2 = al[t][2] + be[t][2];
        float s3 = al[t][3] + be[t][3];
        float m = fmaxf(fmaxf(s0, s1), fmaxf(s2, s3));
        float e0 = expf(s0 - m), e1 = expf(s1 - m), e2 = expf(s2 - m), e3 = expf(s3 - m);
        float p1 = e1 / (e0 + e1 + e2 + e3);
        sp_s[t] = (t < len) ? p1 : 0.f;
    }
    __syncthreads();
    if (tid == 0) {
        float s = 0.f;
        for (int t = 0; t < T_; ++t) s += sp_s[t];
        s_spsum = s;
    }
    __syncthreads();
    const float spsum = s_spsum;
    {
        float acc = 0.f;
        for (int t = 0; t < T_; ++t)
            acc += sp_s[t] * ctx2[((size_t)(b * T_ + t)) * CO_ + tid];
        sv_s[tid] = acc * 2.f / spsum;
    }
    __syncthreads();
    if (tid < 3) {
        float acc = b_lab[tid];
        const float* w = W_lab + tid * CO_;
        for (int c = 0; c < CO_; ++c) acc += sv_s[c] * w[c];
        sred[tid] = acc;
    }
    __syncthreads();
    if (tid == 0) {
        float m = fmaxf(sred[0], fmaxf(sred[1], sred[2]));
        float lse = m + logf(expf(sred[0] - m) + expf(sred[1] - m) + expf(sred[2] - m));
        loss_b[b] = lse - sred[labels[b]];
        spsum_b[b] = spsum;
    }
}

__global__ void k_final(const float* __restrict__ loss_b, const float* __restrict__ spsum_b,
                        const float* __restrict__ trans, float* __restrict__ out) {
    __shared__ float s1[128], s2[128];
    int tid = threadIdx.x;
    s1[tid] = loss_b[tid];
    s2[tid] = spsum_b[tid];
    __syncthreads();
    for (int off = 64; off > 0; off >>= 1) {
        if (tid < off) { s1[tid] += s1[tid + off]; s2[tid] += s2[tid + off]; }
        __syncthreads();
    }
    if (tid == 0) {
        float pena = fmaxf(trans[1 * 4 + 0] - trans[0 * 4 + 0], 0.f)
                   + fmaxf(trans[0 * 4 + 1] - trans[1 * 4 + 1], 0.f);
        out[0] = s1[0] / (float)B_;
        out[1] = 0.1f * pena + 0.1f * (s2[0] / (float)B_);
    }
}

// ---------------- launch ----------------
extern "C" void kernel_launch(void* const* d_in, const int* in_sizes, int n_in,
                              void* d_out, int out_size, void* d_ws, size_t ws_size,
                              hipStream_t stream) {
    const float* sents   = (const float*)d_in[0];
    const int*   masks   = (const int*)d_in[1];
    const int*   labels  = (const int*)d_in[2];
    const int*   lens    = (const int*)d_in[3];
    const float* mask_emb= (const float*)d_in[4];
    const float* Wih_f   = (const float*)d_in[5];
    const float* Whh_f   = (const float*)d_in[6];
    const float* bih_f   = (const float*)d_in[7];
    const float* bhh_f   = (const float*)d_in[8];
    const float* Wih_b   = (const float*)d_in[9];
    const float* Whh_b   = (const float*)d_in[10];
    const float* bih_b   = (const float*)d_in[11];
    const float* bhh_b   = (const float*)d_in[12];
    const float* conv_w  = (const float*)d_in[13];
    const float* conv_b  = (const float*)d_in[14];
    const float* W_tri   = (const float*)d_in[15];
    const float* b_tri   = (const float*)d_in[16];
    const float* trans   = (const float*)d_in[17];
    const float* W_lab   = (const float*)d_in[18];
    const float* b_lab   = (const float*)d_in[19];
    float* out = (float*)d_out;
    float* ws = (float*)d_ws;

    const size_t o_xgf  = 0;
    const size_t o_xgb  = o_xgf  + (size_t)B_ * T_ * G3_;
    const size_t o_ctx  = o_xgb  + (size_t)B_ * T_ * G3_;   // 33.55 MB: sents16 then ctx
    const size_t o_ctx2 = o_ctx  + (size_t)B_ * T_ * D_;    // 16.7 MB: W16 then ctx2
    const size_t o_wp   = o_ctx2 + (size_t)B_ * T_ * CO_;
    const size_t o_me   = o_wp   + (size_t)2 * (H_ / 2) * G3_;
    const size_t o_cwt  = o_me   + 2 * 2 * G3_;
    const size_t o_lossb= o_cwt  + (size_t)D_ * 3 * CO_;
    const size_t o_spsum= o_lossb + B_;

    float* xgf  = ws + o_xgf;
    float* xgb  = ws + o_xgb;
    float* ctx  = ws + o_ctx;
    float* ctx2 = ws + o_ctx2;
    uint_t* wp  = (uint_t*)(ws + o_wp);
    float* me   = ws + o_me;
    float* cwT  = ws + o_cwt;
    float* lossb = ws + o_lossb;
    float* spsumb = ws + o_spsum;

    // sents16 occupies the ctx region (exactly 33,554,432 B each); gemm reads it
    // before k_gru overwrites ctx. W16 (3.1 MB) occupies the ctx2 region head.
    _Float16* sents16 = (_Float16*)ctx;
    _Float16* W16 = (_Float16*)ctx2;

    k_prep_me<<<12, 256, 0, stream>>>(mask_emb, Wih_f, bih_f, Wih_b, bih_b, me);
    k_prep_wh<<<768, 256, 0, stream>>>(Whh_f, Whh_b, wp);
    k_tr_cw<<<1536, 256, 0, stream>>>(conv_w, cwT);
    k_cvt_sents<<<8192, 256, 0, stream>>>(sents, (uint_t*)sents16);
    k_cvt_w<<<768, 256, 0, stream>>>(Wih_f, Wih_b, (uint_t*)W16);
    k_gemm_mfma<<<1536, 256, 0, stream>>>(sents16, W16, me, masks, xgf, xgb);
    k_gru<<<dim3(B_, 2), 256, 0, stream>>>(xgf, xgb, wp, bhh_f, bhh_b, lens, ctx);
    k_conv<<<dim3(8, 128), 256, 0, stream>>>(ctx, cwT, conv_b, ctx2);
    k_head<<<128, 256, 0, stream>>>(ctx2, W_tri, b_tri, trans, W_lab, b_lab,
                                    lens, labels, lossb, spsumb);
    k_final<<<1, 128, 0, stream>>>(lossb, spsumb, trans, out);
}

// Round 5
// 1136.727 us; speedup vs baseline: 2.6365x; 1.0431x over previous
//
#include <hip/hip_runtime.h>
#include <hip/hip_bf16.h>
#include <math.h>

#define B_ 128
#define T_ 128
#define E_ 1024
#define IN_ 1074
#define H_ 256
#define G3_ 768
#define D_ 512
#define CO_ 256

typedef unsigned int uint_t;
typedef _Float16 v2h __attribute__((ext_vector_type(2)));
typedef _Float16 f16x8 __attribute__((ext_vector_type(8)));
typedef float f32x4 __attribute__((ext_vector_type(4)));

// ---------------- prep kernels ----------------

// me[dir][m][g] = bih[g] + sum_c mask_emb[m][c] * Wih[g][1024+c]
__global__ void k_prep_me(const float* __restrict__ mask_emb,
                          const float* __restrict__ Wf, const float* __restrict__ bf,
                          const float* __restrict__ Wb, const float* __restrict__ bb,
                          float* __restrict__ me) {
    int idx = blockIdx.x * 256 + threadIdx.x;   // 0..3071
    if (idx >= 2 * 2 * G3_) return;
    int dir = idx / (2 * G3_);
    int rem = idx % (2 * G3_);
    int m = rem / G3_;
    int g = rem % G3_;
    const float* W = dir ? Wb : Wf;
    const float* bi = dir ? bb : bf;
    float acc = bi[g];
    const float* wrow = W + (size_t)g * IN_ + E_;
    const float* e = mask_emb + m * 50;
    #pragma unroll 10
    for (int c = 0; c < 50; ++c) acc += e[c] * wrow[c];
    me[idx] = acc;
}

__device__ __forceinline__ uint_t pk2(float a, float b) {
    uint_t u0 = (uint_t)__builtin_bit_cast(unsigned short, (_Float16)a);
    uint_t u1 = (uint_t)__builtin_bit_cast(unsigned short, (_Float16)b);
    return u0 | (u1 << 16);
}

// wq layout: flat[(((d*32+q)*3+p)*256 + j)*4 + u] = pk2(W[g][2kp], W[g][2kp+1])
//   where g = p*256+j, kp = 4q+u (q in [0,32), kp in [0,128)).
//   Thread j's 16B chunk for (q,p) is contiguous.
__global__ void k_prep_wh(const float* __restrict__ Wf, const float* __restrict__ Wb,
                          uint_t* __restrict__ wq) {
    int idx = blockIdx.x * 256 + threadIdx.x;   // 0..196607
    if (idx >= 196608) return;
    int u = idx & 3;
    int j = (idx >> 2) & 255;
    int rest = idx >> 10;        // (d*32+q)*3+p
    int p = rest % 3;
    int dq = rest / 3;
    int q = dq & 31;
    int d = dq >> 5;
    int g = p * 256 + j;
    int kp = 4 * q + u;          // [0,128)
    const float* W = d ? Wb : Wf;
    float w0 = W[(size_t)g * H_ + 2 * kp];
    float w1 = W[(size_t)g * H_ + 2 * kp + 1];
    wq[idx] = pk2(w0, w1);
}

// cwT[(d*3+j)*256 + co] = conv_w[co][d][j]
__global__ void k_tr_cw(const float* __restrict__ cw, float* __restrict__ cwT) {
    int i = blockIdx.x * 256 + threadIdx.x;
    if (i >= CO_ * D_ * 3) return;
    int co = i & 255;
    int dj = i >> 8;                // d*3+j
    cwT[i] = cw[(size_t)co * (D_ * 3) + dj];
}

// sents f32 -> f16 (packed). 16,777,216 elems, 8 per thread.
__global__ __launch_bounds__(256) void k_cvt_sents(const float* __restrict__ in,
                                                   uint_t* __restrict__ out) {
    int i = blockIdx.x * 256 + threadIdx.x;    // 0..2097151
    float4 a = reinterpret_cast<const float4*>(in)[i * 2];
    float4 b = reinterpret_cast<const float4*>(in)[i * 2 + 1];
    uint4 o;
    o.x = pk2(a.x, a.y); o.y = pk2(a.z, a.w);
    o.z = pk2(b.x, b.y); o.w = pk2(b.z, b.w);
    reinterpret_cast<uint4*>(out)[i] = o;
}

// W16[n][k] = f16(Wih_dir[g][k]), n = dir*768+g, k<1024 (row stride IN_=1074)
__global__ __launch_bounds__(256) void k_cvt_w(const float* __restrict__ Wf,
                                               const float* __restrict__ Wb,
                                               uint_t* __restrict__ out) {
    int i = blockIdx.x * 256 + threadIdx.x;    // 0..196607 (1536*128)
    if (i >= 1536 * 128) return;
    int n = i >> 7, kq = i & 127;
    int dir = n >= G3_;
    int g = n - dir * G3_;
    const float* src = (dir ? Wb : Wf) + (size_t)g * IN_ + kq * 8;
    float2 a = reinterpret_cast<const float2*>(src)[0];
    float2 b = reinterpret_cast<const float2*>(src)[1];
    float2 c = reinterpret_cast<const float2*>(src)[2];
    float2 d = reinterpret_cast<const float2*>(src)[3];
    uint4 o;
    o.x = pk2(a.x, a.y); o.y = pk2(b.x, b.y);
    o.z = pk2(c.x, c.y); o.w = pk2(d.x, d.y);
    reinterpret_cast<uint4*>(out)[i] = o;
}

// ---------------- MFMA xg GEMM ----------------

__device__ __forceinline__ void gload16(const void* g, void* l) {
    __builtin_amdgcn_global_load_lds(
        (const __attribute__((address_space(1))) void*)g,
        (__attribute__((address_space(3))) void*)l, 16, 0, 0);
}

__global__ __launch_bounds__(256) void k_gemm_mfma(
        const _Float16* __restrict__ A16, const _Float16* __restrict__ W16,
        const float* __restrict__ me, const int* __restrict__ masks,
        float* __restrict__ xgf, float* __restrict__ xgb) {
    __shared__ _Float16 As[4096];
    __shared__ _Float16 Bs[4096];
    const int bid = blockIdx.x;
    const int logical = (bid & 7) * 192 + (bid >> 3);   // XCD-contiguous chunks
    const int mt = logical / 12, nt = logical % 12;
    const int bm = mt * 128, bn = nt * 128;
    const int tid = threadIdx.x;
    const int w = tid >> 6, lane = tid & 63;
    const int wr = w >> 1, wc = w & 1;

    const int rl = lane & 15;
    const int kb = (lane >> 4) * 16;
    const int st0 = w, st1 = 4 + w;
    const char* gA0 = (const char*)A16 + (size_t)(bm + st0 * 16 + rl) * 2048 + kb;
    const char* gA1 = (const char*)A16 + (size_t)(bm + st1 * 16 + rl) * 2048 + kb;
    const char* gB0 = (const char*)W16 + (size_t)(bn + st0 * 16 + rl) * 2048 + kb;
    const char* gB1 = (const char*)W16 + (size_t)(bn + st1 * 16 + rl) * 2048 + kb;
    char* lA0 = (char*)As + w * 1024;
    char* lA1 = (char*)As + 4096 + w * 1024;
    char* lB0 = (char*)Bs + w * 1024;
    char* lB1 = (char*)Bs + 4096 + w * 1024;

    f32x4 acc[4][4];
    #pragma unroll
    for (int m = 0; m < 4; ++m)
        #pragma unroll
        for (int n = 0; n < 4; ++n)
            acc[m][n] = (f32x4){0.f, 0.f, 0.f, 0.f};

    for (int kB = 0; kB < 2048; kB += 64) {
        gload16(gA0 + kB, lA0);
        gload16(gA1 + kB, lA1);
        gload16(gB0 + kB, lB0);
        gload16(gB1 + kB, lB1);
        __syncthreads();
        f16x8 af[4], bf[4];
        #pragma unroll
        for (int m = 0; m < 4; ++m)
            af[m] = *reinterpret_cast<const f16x8*>(
                (const char*)As + (wr * 4 + m) * 1024 + lane * 16);
        #pragma unroll
        for (int n = 0; n < 4; ++n)
            bf[n] = *reinterpret_cast<const f16x8*>(
                (const char*)Bs + (wc * 4 + n) * 1024 + lane * 16);
        #pragma unroll
        for (int m = 0; m < 4; ++m)
            #pragma unroll
            for (int n = 0; n < 4; ++n)
                acc[m][n] = __builtin_amdgcn_mfma_f32_16x16x32_f16(
                    af[m], bf[n], acc[m][n], 0, 0, 0);
        __syncthreads();
    }

    const int qr = (lane >> 4) * 4;
    const int cc = lane & 15;
    #pragma unroll
    for (int m = 0; m < 4; ++m) {
        #pragma unroll
        for (int q = 0; q < 4; ++q) {
            const int bt = bm + wr * 64 + m * 16 + qr + q;
            const int mk = masks[bt];
            const int b = bt >> 7, t = bt & 127;
            #pragma unroll
            for (int n = 0; n < 4; ++n) {
                const int col = bn + wc * 64 + n * 16 + cc;
                const int dir = col >= G3_;
                const int g = col - dir * G3_;
                float v = acc[m][n][q] + me[dir * (2 * G3_) + mk * G3_ + g];
                float* dst = (dir ? xgb : xgf) + ((size_t)(t * B_ + b)) * G3_ + g;
                *dst = v;
            }
        }
    }
}

// ---------------- GRU scan ----------------
__device__ __forceinline__ float dot2(uint_t w, uint_t h, float acc) {
#if __has_builtin(__builtin_amdgcn_fdot2)
    return __builtin_amdgcn_fdot2(__builtin_bit_cast(v2h, w),
                                  __builtin_bit_cast(v2h, h), acc, false);
#else
    v2h a = __builtin_bit_cast(v2h, w), b = __builtin_bit_cast(v2h, h);
    return acc + (float)a[0] * (float)b[0] + (float)a[1] * (float)b[1];
#endif
}

// One block = (pair of batch rows, direction). 256 threads; thread j owns hidden
// unit j for BOTH rows (weight stream fetched once, dotted twice).
__global__ __launch_bounds__(256) void k_gru(
        const float* __restrict__ xgf, const float* __restrict__ xgb,
        const uint_t* __restrict__ wq,
        const float* __restrict__ bhhf, const float* __restrict__ bhhb,
        const int* __restrict__ lens, float* __restrict__ ctx) {
    const int dir = blockIdx.y;
    const int b0 = blockIdx.x * 2;
    const int j = threadIdx.x;
    const float* xg = dir ? xgb : xgf;
    const uint4* wbase = (const uint4*)wq + (size_t)dir * (32 * 3 * 256);
    const float* bhh = dir ? bhhb : bhhf;
    __shared__ uint_t h2s[2][2][128];
    if (j < 128) { h2s[0][0][j] = 0u; h2s[0][1][j] = 0u; }
    const int len0 = lens[b0], len1 = lens[b0 + 1];
    const float bh0 = bhh[j], bh1 = bhh[H_ + j], bh2 = bhh[2 * H_ + j];
    float h0 = 0.f, h1 = 0.f;
    __syncthreads();
    for (int s = 0; s < T_; ++s) {
        const int t = dir ? (T_ - 1 - s) : s;
        const int cur = s & 1, nxt = cur ^ 1;
        const float* gga = xg + ((size_t)(t * B_ + b0)) * G3_;
        const float* ggb = gga + G3_;
        float g0a = gga[j], g1a = gga[H_ + j], g2a = gga[2 * H_ + j];
        float g0b = ggb[j], g1b = ggb[H_ + j], g2b = ggb[2 * H_ + j];
        float a00 = 0.f, a01 = 0.f, a02 = 0.f;
        float a10 = 0.f, a11 = 0.f, a12 = 0.f;
        #pragma unroll 4
        for (int q = 0; q < 32; ++q) {     // 32 chunks x 4 pairs x 2 = 256 = H
            uint4 hp0 = *reinterpret_cast<const uint4*>(&h2s[cur][0][q * 4]);
            uint4 hp1 = *reinterpret_cast<const uint4*>(&h2s[cur][1][q * 4]);
            const uint4* wk = wbase + (size_t)q * 768 + j;
            uint4 w0 = wk[0];
            uint4 w1 = wk[256];
            uint4 w2 = wk[512];
            a00 = dot2(w0.x, hp0.x, a00); a00 = dot2(w0.y, hp0.y, a00);
            a00 = dot2(w0.z, hp0.z, a00); a00 = dot2(w0.w, hp0.w, a00);
            a10 = dot2(w0.x, hp1.x, a10); a10 = dot2(w0.y, hp1.y, a10);
            a10 = dot2(w0.z, hp1.z, a10); a10 = dot2(w0.w, hp1.w, a10);
            a01 = dot2(w1.x, hp0.x, a01); a01 = dot2(w1.y, hp0.y, a01);
            a01 = dot2(w1.z, hp0.z, a01); a01 = dot2(w1.w, hp0.w, a01);
            a11 = dot2(w1.x, hp1.x, a11); a11 = dot2(w1.y, hp1.y, a11);
            a11 = dot2(w1.z, hp1.z, a11); a11 = dot2(w1.w, hp1.w, a11);
            a02 = dot2(w2.x, hp0.x, a02); a02 = dot2(w2.y, hp0.y, a02);
            a02 = dot2(w2.z, hp0.z, a02); a02 = dot2(w2.w, hp0.w, a02);
            a12 = dot2(w2.x, hp1.x, a12); a12 = dot2(w2.y, hp1.y, a12);
            a12 = dot2(w2.z, hp1.z, a12); a12 = dot2(w2.w, hp1.w, a12);
        }
        float rg0 = 1.f / (1.f + expf(-(g0a + a00 + bh0)));
        float zg0 = 1.f / (1.f + expf(-(g1a + a01 + bh1)));
        float ng0 = tanhf(g2a + rg0 * (a02 + bh2));
        float v0 = (1.f - zg0) * ng0 + zg0 * h0;
        h0 = (t < len0) ? v0 : h0;
        float rg1 = 1.f / (1.f + expf(-(g0b + a10 + bh0)));
        float zg1 = 1.f / (1.f + expf(-(g1b + a11 + bh1)));
        float ng1 = tanhf(g2b + rg1 * (a12 + bh2));
        float v1 = (1.f - zg1) * ng1 + zg1 * h1;
        h1 = (t < len1) ? v1 : h1;
        ctx[((size_t)(b0 * T_ + t)) * D_ + dir * H_ + j] = h0;
        ctx[((size_t)((b0 + 1) * T_ + t)) * D_ + dir * H_ + j] = h1;
        ((_Float16*)&h2s[nxt][0][0])[j] = (_Float16)h0;
        ((_Float16*)&h2s[nxt][1][0])[j] = (_Float16)h1;
        __syncthreads();
    }
}

// ---------------- conv1d (D->CO, k=3, pad=1) + ReLU ----------------
__global__ __launch_bounds__(256) void k_conv(
        const float* __restrict__ ctx, const float* __restrict__ cwT,
        const float* __restrict__ cb, float* __restrict__ ctx2) {
    const int b = blockIdx.y;
    const int t0 = blockIdx.x * 16;
    const int tid = threadIdx.x;
    __shared__ float s[18][D_];
    for (int i = tid; i < 18 * D_ / 4; i += 256) {
        int flat = i * 4;
        int row = flat >> 9;
        int col = flat & (D_ - 1);
        int t = t0 - 1 + row;
        float4 v = make_float4(0.f, 0.f, 0.f, 0.f);
        if (t >= 0 && t < T_)
            v = *reinterpret_cast<const float4*>(ctx + ((size_t)(b * T_ + t)) * D_ + col);
        *reinterpret_cast<float4*>(&s[row][col]) = v;
    }
    __syncthreads();
    float acc[16];
    const float bias = cb[tid];
    #pragma unroll
    for (int i = 0; i < 16; ++i) acc[i] = bias;
    for (int d = 0; d < D_; d += 4) {
        float vv[72];
        #pragma unroll
        for (int r = 0; r < 18; ++r) {
            float4 q = *reinterpret_cast<const float4*>(&s[r][d]);
            vv[r * 4 + 0] = q.x; vv[r * 4 + 1] = q.y;
            vv[r * 4 + 2] = q.z; vv[r * 4 + 3] = q.w;
        }
        #pragma unroll
        for (int sub = 0; sub < 4; ++sub) {
            float w0 = cwT[((d + sub) * 3 + 0) * CO_ + tid];
            float w1 = cwT[((d + sub) * 3 + 1) * CO_ + tid];
            float w2 = cwT[((d + sub) * 3 + 2) * CO_ + tid];
            #pragma unroll
            for (int ti = 0; ti < 16; ++ti) {
                acc[ti] += w0 * vv[(ti + 0) * 4 + sub];
                acc[ti] += w1 * vv[(ti + 1) * 4 + sub];
                acc[ti] += w2 * vv[(ti + 2) * 4 + sub];
            }
        }
    }
    #pragma unroll
    for (int ti = 0; ti < 16; ++ti) {
        ctx2[((size_t)(b * T_ + t0 + ti)) * CO_ + tid] = fmaxf(acc[ti], 0.f);
    }
}

// ---------------- feats + CRF + pooled head ----------------
__global__ __launch_bounds__(256) void k_head(
        const float* __restrict__ ctx2, const float* __restrict__ W_tri,
        const float* __restrict__ b_tri, const float* __restrict__ trans,
        const float* __restrict__ W_lab, const float* __restrict__ b_lab,
        const int* __restrict__ lens, const int* __restrict__ labels,
        float* __restrict__ loss_b, float* __restrict__ spsum_b) {
    const int b = blockIdx.x;
    const int tid = threadIdx.x;
    __shared__ float f_s[T_][4];
    __shared__ float al[T_][4];
    __shared__ float be[T_][4];
    __shared__ float sp_s[T_];
    __shared__ float sv_s[CO_];
    __shared__ float sred[3];
    __shared__ float s_spsum;
    const int len = lens[b];
    for (int idx = tid; idx < T_ * 4; idx += 256) {
        int t = idx >> 2, k = idx & 3;
        const float* row = ctx2 + ((size_t)(b * T_ + t)) * CO_;
        const float* w = W_tri + k * CO_;
        float acc = b_tri[k];
        for (int c = 0; c < CO_; ++c) acc += row[c] * w[c];
        f_s[t][k] = acc;
    }
    __syncthreads();
    if (tid == 0) {
        float Tr[16];
        #pragma unroll
        for (int i = 0; i < 16; ++i) Tr[i] = trans[i];
        float a[4];
        #pragma unroll
        for (int k = 0; k < 4; ++k) { a[k] = f_s[0][k]; al[0][k] = a[k]; }
        for (int t = 1; t < T_; ++t) {
            float an[4];
            #pragma unroll
            for (int j = 0; j < 4; ++j) {
                float m = a[0] + Tr[0 * 4 + j];
                #pragma unroll
                for (int i = 1; i < 4; ++i) m = fmaxf(m, a[i] + Tr[i * 4 + j]);
                float sum = 0.f;
                #pragma unroll
                for (int i = 0; i < 4; ++i) sum += expf(a[i] + Tr[i * 4 + j] - m);
                an[j] = f_s[t][j] + m + logf(sum);
            }
            if (t < len) {
                #pragma unroll
                for (int k = 0; k < 4; ++k) a[k] = an[k];
            }
            #pragma unroll
            for (int k = 0; k < 4; ++k) al[t][k] = a[k];
        }
    } else if (tid == 64) {
        float Tr[16];
        #pragma unroll
        for (int i = 0; i < 16; ++i) Tr[i] = trans[i];
        float bb[4] = {0, 0, 0, 0};
        #pragma unroll
        for (int k = 0; k < 4; ++k) be[T_ - 1][k] = 0.f;
        for (int t = T_ - 2; t >= 0; --t) {
            float bn[4];
            #pragma unroll
            for (int i = 0; i < 4; ++i) {
                float m = Tr[i * 4 + 0] + f_s[t + 1][0] + bb[0];
                #pragma unroll
                for (int j = 1; j < 4; ++j) m = fmaxf(m, Tr[i * 4 + j] + f_s[t + 1][j] + bb[j]);
                float sum = 0.f;
                #pragma unroll
                for (int j = 0; j < 4; ++j) sum += expf(Tr[i * 4 + j] + f_s[t + 1][j] + bb[j] - m);
                bn[i] = m + logf(sum);
            }
            if (t + 1 < len) {
                #pragma unroll
                for (int k = 0; k < 4; ++k) bb[k] = bn[k];
            }
            #pragma unroll
            for (int k = 0; k < 4; ++k) be[t][k] = bb[k];
        }
    }
    __syncthreads();
    if (tid < T_) {
        int t = tid;
        float s0 = al[t][0] + be[t][0];
        float s1 = al[t][1] + be[t][1];
        float s2 = al[t][2] + be[t][2];
        float s3 = al[t][3] + be[t][3];
        float m = fmaxf(fmaxf(s0, s1), fmaxf(s2, s3));
        float e0 = expf(s0 - m), e1 = expf(s1 - m), e2 = expf(s2 - m), e3 = expf(s3 - m);
        float p1 = e1 / (e0 + e1 + e2 + e3);
        sp_s[t] = (t < len) ? p1 : 0.f;
    }
    __syncthreads();
    if (tid == 0) {
        float s = 0.f;
        for (int t = 0; t < T_; ++t) s += sp_s[t];
        s_spsum = s;
    }
    __syncthreads();
    const float spsum = s_spsum;
    {
        float acc = 0.f;
        for (int t = 0; t < T_; ++t)
            acc += sp_s[t] * ctx2[((size_t)(b * T_ + t)) * CO_ + tid];
        sv_s[tid] = acc * 2.f / spsum;
    }
    __syncthreads();
    if (tid < 3) {
        float acc = b_lab[tid];
        const float* w = W_lab + tid * CO_;
        for (int c = 0; c < CO_; ++c) acc += sv_s[c] * w[c];
        sred[tid] = acc;
    }
    __syncthreads();
    if (tid == 0) {
        float m = fmaxf(sred[0], fmaxf(sred[1], sred[2]));
        float lse = m + logf(expf(sred[0] - m) + expf(sred[1] - m) + expf(sred[2] - m));
        loss_b[b] = lse - sred[labels[b]];
        spsum_b[b] = spsum;
    }
}

__global__ void k_final(const float* __restrict__ loss_b, const float* __restrict__ spsum_b,
                        const float* __restrict__ trans, float* __restrict__ out) {
    __shared__ float s1[128], s2[128];
    int tid = threadIdx.x;
    s1[tid] = loss_b[tid];
    s2[tid] = spsum_b[tid];
    __syncthreads();
    for (int off = 64; off > 0; off >>= 1) {
        if (tid < off) { s1[tid] += s1[tid + off]; s2[tid] += s2[tid + off]; }
        __syncthreads();
    }
    if (tid == 0) {
        float pena = fmaxf(trans[1 * 4 + 0] - trans[0 * 4 + 0], 0.f)
                   + fmaxf(trans[0 * 4 + 1] - trans[1 * 4 + 1], 0.f);
        out[0] = s1[0] / (float)B_;
        out[1] = 0.1f * pena + 0.1f * (s2[0] / (float)B_);
    }
}

// ---------------- launch ----------------
extern "C" void kernel_launch(void* const* d_in, const int* in_sizes, int n_in,
                              void* d_out, int out_size, void* d_ws, size_t ws_size,
                              hipStream_t stream) {
    const float* sents   = (const float*)d_in[0];
    const int*   masks   = (const int*)d_in[1];
    const int*   labels  = (const int*)d_in[2];
    const int*   lens    = (const int*)d_in[3];
    const float* mask_emb= (const float*)d_in[4];
    const float* Wih_f   = (const float*)d_in[5];
    const float* Whh_f   = (const float*)d_in[6];
    const float* bih_f   = (const float*)d_in[7];
    const float* bhh_f   = (const float*)d_in[8];
    const float* Wih_b   = (const float*)d_in[9];
    const float* Whh_b   = (const float*)d_in[10];
    const float* bih_b   = (const float*)d_in[11];
    const float* bhh_b   = (const float*)d_in[12];
    const float* conv_w  = (const float*)d_in[13];
    const float* conv_b  = (const float*)d_in[14];
    const float* W_tri   = (const float*)d_in[15];
    const float* b_tri   = (const float*)d_in[16];
    const float* trans   = (const float*)d_in[17];
    const float* W_lab   = (const float*)d_in[18];
    const float* b_lab   = (const float*)d_in[19];
    float* out = (float*)d_out;
    float* ws = (float*)d_ws;

    const size_t o_xgf  = 0;
    const size_t o_xgb  = o_xgf  + (size_t)B_ * T_ * G3_;
    const size_t o_ctx  = o_xgb  + (size_t)B_ * T_ * G3_;   // sents16 then ctx
    const size_t o_ctx2 = o_ctx  + (size_t)B_ * T_ * D_;    // W16 then ctx2
    const size_t o_wp   = o_ctx2 + (size_t)B_ * T_ * CO_;
    const size_t o_me   = o_wp   + (size_t)2 * 32 * 3 * 256 * 4;  // 196608 uints
    const size_t o_cwt  = o_me   + 2 * 2 * G3_;
    const size_t o_lossb= o_cwt  + (size_t)D_ * 3 * CO_;
    const size_t o_spsum= o_lossb + B_;

    float* xgf  = ws + o_xgf;
    float* xgb  = ws + o_xgb;
    float* ctx  = ws + o_ctx;
    float* ctx2 = ws + o_ctx2;
    uint_t* wq  = (uint_t*)(ws + o_wp);
    float* me   = ws + o_me;
    float* cwT  = ws + o_cwt;
    float* lossb = ws + o_lossb;
    float* spsumb = ws + o_spsum;

    _Float16* sents16 = (_Float16*)ctx;
    _Float16* W16 = (_Float16*)ctx2;

    k_prep_me<<<12, 256, 0, stream>>>(mask_emb, Wih_f, bih_f, Wih_b, bih_b, me);
    k_prep_wh<<<768, 256, 0, stream>>>(Whh_f, Whh_b, wq);
    k_tr_cw<<<1536, 256, 0, stream>>>(conv_w, cwT);
    k_cvt_sents<<<8192, 256, 0, stream>>>(sents, (uint_t*)sents16);
    k_cvt_w<<<768, 256, 0, stream>>>(Wih_f, Wih_b, (uint_t*)W16);
    k_gemm_mfma<<<1536, 256, 0, stream>>>(sents16, W16, me, masks, xgf, xgb);
    k_gru<<<dim3(B_ / 2, 2), 256, 0, stream>>>(xgf, xgb, wq, bhh_f, bhh_b, lens, ctx);
    k_conv<<<dim3(8, 128), 256, 0, stream>>>(ctx, cwT, conv_b, ctx2);
    k_head<<<128, 256, 0, stream>>>(ctx2, W_tri, b_tri, trans, W_lab, b_lab,
                                    lens, labels, lossb, spsumb);
    k_final<<<1, 128, 0, stream>>>(lossb, spsumb, trans, out);
}

// Round 6
// 754.719 us; speedup vs baseline: 3.9710x; 1.5062x over previous
//
#include <hip/hip_runtime.h>
#include <hip/hip_bf16.h>
#include <math.h>

#define B_ 128
#define T_ 128
#define E_ 1024
#define IN_ 1074
#define H_ 256
#define G3_ 768
#define D_ 512
#define CO_ 256

typedef unsigned int uint_t;
typedef _Float16 v2h __attribute__((ext_vector_type(2)));
typedef _Float16 f16x8 __attribute__((ext_vector_type(8)));
typedef float f32x4 __attribute__((ext_vector_type(4)));

// ---------------- prep kernels ----------------

// me[dir][m][g] = bih[g] + sum_c mask_emb[m][c] * Wih[g][1024+c]
__global__ void k_prep_me(const float* __restrict__ mask_emb,
                          const float* __restrict__ Wf, const float* __restrict__ bf,
                          const float* __restrict__ Wb, const float* __restrict__ bb,
                          float* __restrict__ me) {
    int idx = blockIdx.x * 256 + threadIdx.x;   // 0..3071
    if (idx >= 2 * 2 * G3_) return;
    int dir = idx / (2 * G3_);
    int rem = idx % (2 * G3_);
    int m = rem / G3_;
    int g = rem % G3_;
    const float* W = dir ? Wb : Wf;
    const float* bi = dir ? bb : bf;
    float acc = bi[g];
    const float* wrow = W + (size_t)g * IN_ + E_;
    const float* e = mask_emb + m * 50;
    #pragma unroll 10
    for (int c = 0; c < 50; ++c) acc += e[c] * wrow[c];
    me[idx] = acc;
}

__device__ __forceinline__ uint_t pk2(float a, float b) {
    uint_t u0 = (uint_t)__builtin_bit_cast(unsigned short, (_Float16)a);
    uint_t u1 = (uint_t)__builtin_bit_cast(unsigned short, (_Float16)b);
    return u0 | (u1 << 16);
}

// wq layout: flat[(((d*32+q)*3+p)*256 + j)*4 + u] = pk2(W[g][2kp], W[g][2kp+1])
//   where g = p*256+j, kp = 4q+u (q in [0,32), kp in [0,128)).
//   Thread j's 16B chunk for (q,p) is contiguous.
__global__ void k_prep_wh(const float* __restrict__ Wf, const float* __restrict__ Wb,
                          uint_t* __restrict__ wq) {
    int idx = blockIdx.x * 256 + threadIdx.x;   // 0..196607
    if (idx >= 196608) return;
    int u = idx & 3;
    int j = (idx >> 2) & 255;
    int rest = idx >> 10;        // (d*32+q)*3+p
    int p = rest % 3;
    int dq = rest / 3;
    int q = dq & 31;
    int d = dq >> 5;
    int g = p * 256 + j;
    int kp = 4 * q + u;          // [0,128)
    const float* W = d ? Wb : Wf;
    float w0 = W[(size_t)g * H_ + 2 * kp];
    float w1 = W[(size_t)g * H_ + 2 * kp + 1];
    wq[idx] = pk2(w0, w1);
}

// cwT[(d*3+j)*256 + co] = conv_w[co][d][j]
__global__ void k_tr_cw(const float* __restrict__ cw, float* __restrict__ cwT) {
    int i = blockIdx.x * 256 + threadIdx.x;
    if (i >= CO_ * D_ * 3) return;
    int co = i & 255;
    int dj = i >> 8;                // d*3+j
    cwT[i] = cw[(size_t)co * (D_ * 3) + dj];
}

// sents f32 -> f16 (packed). 16,777,216 elems, 8 per thread.
__global__ __launch_bounds__(256) void k_cvt_sents(const float* __restrict__ in,
                                                   uint_t* __restrict__ out) {
    int i = blockIdx.x * 256 + threadIdx.x;    // 0..2097151
    float4 a = reinterpret_cast<const float4*>(in)[i * 2];
    float4 b = reinterpret_cast<const float4*>(in)[i * 2 + 1];
    uint4 o;
    o.x = pk2(a.x, a.y); o.y = pk2(a.z, a.w);
    o.z = pk2(b.x, b.y); o.w = pk2(b.z, b.w);
    reinterpret_cast<uint4*>(out)[i] = o;
}

// W16[n][k] = f16(Wih_dir[g][k]), n = dir*768+g, k<1024 (row stride IN_=1074)
__global__ __launch_bounds__(256) void k_cvt_w(const float* __restrict__ Wf,
                                               const float* __restrict__ Wb,
                                               uint_t* __restrict__ out) {
    int i = blockIdx.x * 256 + threadIdx.x;    // 0..196607 (1536*128)
    if (i >= 1536 * 128) return;
    int n = i >> 7, kq = i & 127;
    int dir = n >= G3_;
    int g = n - dir * G3_;
    const float* src = (dir ? Wb : Wf) + (size_t)g * IN_ + kq * 8;
    float2 a = reinterpret_cast<const float2*>(src)[0];
    float2 b = reinterpret_cast<const float2*>(src)[1];
    float2 c = reinterpret_cast<const float2*>(src)[2];
    float2 d = reinterpret_cast<const float2*>(src)[3];
    uint4 o;
    o.x = pk2(a.x, a.y); o.y = pk2(b.x, b.y);
    o.z = pk2(c.x, c.y); o.w = pk2(d.x, d.y);
    reinterpret_cast<uint4*>(out)[i] = o;
}

// ---------------- MFMA xg GEMM ----------------

__device__ __forceinline__ void gload16(const void* g, void* l) {
    __builtin_amdgcn_global_load_lds(
        (const __attribute__((address_space(1))) void*)g,
        (__attribute__((address_space(3))) void*)l, 16, 0, 0);
}

__global__ __launch_bounds__(256) void k_gemm_mfma(
        const _Float16* __restrict__ A16, const _Float16* __restrict__ W16,
        const float* __restrict__ me, const int* __restrict__ masks,
        float* __restrict__ xgf, float* __restrict__ xgb) {
    __shared__ _Float16 As[4096];
    __shared__ _Float16 Bs[4096];
    const int bid = blockIdx.x;
    const int logical = (bid & 7) * 192 + (bid >> 3);   // XCD-contiguous chunks
    const int mt = logical / 12, nt = logical % 12;
    const int bm = mt * 128, bn = nt * 128;
    const int tid = threadIdx.x;
    const int w = tid >> 6, lane = tid & 63;
    const int wr = w >> 1, wc = w & 1;

    const int rl = lane & 15;
    const int kb = (lane >> 4) * 16;
    const int st0 = w, st1 = 4 + w;
    const char* gA0 = (const char*)A16 + (size_t)(bm + st0 * 16 + rl) * 2048 + kb;
    const char* gA1 = (const char*)A16 + (size_t)(bm + st1 * 16 + rl) * 2048 + kb;
    const char* gB0 = (const char*)W16 + (size_t)(bn + st0 * 16 + rl) * 2048 + kb;
    const char* gB1 = (const char*)W16 + (size_t)(bn + st1 * 16 + rl) * 2048 + kb;
    char* lA0 = (char*)As + w * 1024;
    char* lA1 = (char*)As + 4096 + w * 1024;
    char* lB0 = (char*)Bs + w * 1024;
    char* lB1 = (char*)Bs + 4096 + w * 1024;

    f32x4 acc[4][4];
    #pragma unroll
    for (int m = 0; m < 4; ++m)
        #pragma unroll
        for (int n = 0; n < 4; ++n)
            acc[m][n] = (f32x4){0.f, 0.f, 0.f, 0.f};

    for (int kB = 0; kB < 2048; kB += 64) {
        gload16(gA0 + kB, lA0);
        gload16(gA1 + kB, lA1);
        gload16(gB0 + kB, lB0);
        gload16(gB1 + kB, lB1);
        __syncthreads();
        f16x8 af[4], bf[4];
        #pragma unroll
        for (int m = 0; m < 4; ++m)
            af[m] = *reinterpret_cast<const f16x8*>(
                (const char*)As + (wr * 4 + m) * 1024 + lane * 16);
        #pragma unroll
        for (int n = 0; n < 4; ++n)
            bf[n] = *reinterpret_cast<const f16x8*>(
                (const char*)Bs + (wc * 4 + n) * 1024 + lane * 16);
        #pragma unroll
        for (int m = 0; m < 4; ++m)
            #pragma unroll
            for (int n = 0; n < 4; ++n)
                acc[m][n] = __builtin_amdgcn_mfma_f32_16x16x32_f16(
                    af[m], bf[n], acc[m][n], 0, 0, 0);
        __syncthreads();
    }

    const int qr = (lane >> 4) * 4;
    const int cc = lane & 15;
    #pragma unroll
    for (int m = 0; m < 4; ++m) {
        #pragma unroll
        for (int q = 0; q < 4; ++q) {
            const int bt = bm + wr * 64 + m * 16 + qr + q;
            const int mk = masks[bt];
            const int b = bt >> 7, t = bt & 127;
            #pragma unroll
            for (int n = 0; n < 4; ++n) {
                const int col = bn + wc * 64 + n * 16 + cc;
                const int dir = col >= G3_;
                const int g = col - dir * G3_;
                float v = acc[m][n][q] + me[dir * (2 * G3_) + mk * G3_ + g];
                float* dst = (dir ? xgb : xgf) + ((size_t)(t * B_ + b)) * G3_ + g;
                *dst = v;
            }
        }
    }
}

// ---------------- GRU scan (weights in registers) ----------------
__device__ __forceinline__ float dot2(uint_t w, uint_t h, float acc) {
#if __has_builtin(__builtin_amdgcn_fdot2)
    return __builtin_amdgcn_fdot2(__builtin_bit_cast(v2h, w),
                                  __builtin_bit_cast(v2h, h), acc, false);
#else
    v2h a = __builtin_bit_cast(v2h, w), b = __builtin_bit_cast(v2h, h);
    return acc + (float)a[0] * (float)b[0] + (float)a[1] * (float)b[1];
#endif
}

// One block = one (batch row, direction). 512 threads: j = tid&255 owns hidden
// unit j; half = tid>>8 covers k in [half*128, half*128+128). Whh lives in
// 192 VGPRs/thread (48 uint4), loaded once; inner loop is pure VALU + LDS.
__global__ __launch_bounds__(512, 2) void k_gru(
        const float* __restrict__ xgf, const float* __restrict__ xgb,
        const uint_t* __restrict__ wq,
        const float* __restrict__ bhhf, const float* __restrict__ bhhb,
        const int* __restrict__ lens, float* __restrict__ ctx) {
    const int dir = blockIdx.y;
    const int b = blockIdx.x;
    const int tid = threadIdx.x;
    const int j = tid & 255;
    const int half = tid >> 8;
    const float* xg = dir ? xgb : xgf;
    const float* bhh = dir ? bhhb : bhhf;
    const uint4* wq4 = (const uint4*)wq + (size_t)dir * (32 * 3 * 256);

    __shared__ uint4 hs4[32];            // 256 f16 h values
    __shared__ float part[3][256];
    _Float16* hsf = (_Float16*)hs4;

    // load weights: w4[p][c] for chunk q = half*16 + c
    uint4 w4[3][16];
    #pragma unroll
    for (int c = 0; c < 16; ++c) {
        const int q = half * 16 + c;
        #pragma unroll
        for (int p = 0; p < 3; ++p)
            w4[p][c] = wq4[((size_t)q * 3 + p) * 256 + j];
    }

    if (tid < 32) hs4[tid] = (uint4){0u, 0u, 0u, 0u};
    const int len = lens[b];
    const float bh0 = bhh[j], bh1 = bhh[H_ + j], bh2 = bhh[2 * H_ + j];
    float hcur = 0.f;
    float g0 = 0.f, g1 = 0.f, g2 = 0.f;
    int t = dir ? (T_ - 1) : 0;
    if (half == 0) {
        const float* r = xg + ((size_t)(t * B_ + b)) * G3_;
        g0 = r[j]; g1 = r[H_ + j]; g2 = r[2 * H_ + j];
    }
    __syncthreads();

    for (int s = 0; s < T_; ++s) {
        const int tn = dir ? (T_ - 2 - s) : (s + 1);
        float n0 = 0.f, n1 = 0.f, n2 = 0.f;
        if (half == 0 && s < T_ - 1) {
            const float* r = xg + ((size_t)(tn * B_ + b)) * G3_;
            n0 = r[j]; n1 = r[H_ + j]; n2 = r[2 * H_ + j];
        }
        float a0 = 0.f, a1 = 0.f, a2 = 0.f;
        #pragma unroll
        for (int c = 0; c < 16; ++c) {
            uint4 hp = hs4[half * 16 + c];
            a0 = dot2(w4[0][c].x, hp.x, a0); a0 = dot2(w4[0][c].y, hp.y, a0);
            a0 = dot2(w4[0][c].z, hp.z, a0); a0 = dot2(w4[0][c].w, hp.w, a0);
            a1 = dot2(w4[1][c].x, hp.x, a1); a1 = dot2(w4[1][c].y, hp.y, a1);
            a1 = dot2(w4[1][c].z, hp.z, a1); a1 = dot2(w4[1][c].w, hp.w, a1);
            a2 = dot2(w4[2][c].x, hp.x, a2); a2 = dot2(w4[2][c].y, hp.y, a2);
            a2 = dot2(w4[2][c].z, hp.z, a2); a2 = dot2(w4[2][c].w, hp.w, a2);
        }
        if (half == 1) {
            part[0][j] = a0; part[1][j] = a1; part[2][j] = a2;
        }
        __syncthreads();
        if (half == 0) {
            a0 += part[0][j]; a1 += part[1][j]; a2 += part[2][j];
            float rg = 1.f / (1.f + expf(-(g0 + a0 + bh0)));
            float zg = 1.f / (1.f + expf(-(g1 + a1 + bh1)));
            float ng = tanhf(g2 + rg * (a2 + bh2));
            float v = (1.f - zg) * ng + zg * hcur;
            hcur = (t < len) ? v : hcur;
            ctx[((size_t)(b * T_ + t)) * D_ + dir * H_ + j] = hcur;
            hsf[j] = (_Float16)hcur;
        }
        __syncthreads();
        g0 = n0; g1 = n1; g2 = n2;
        t = tn;
    }
}

// ---------------- conv1d (D->CO, k=3, pad=1) + ReLU ----------------
__global__ __launch_bounds__(256) void k_conv(
        const float* __restrict__ ctx, const float* __restrict__ cwT,
        const float* __restrict__ cb, float* __restrict__ ctx2) {
    const int b = blockIdx.y;
    const int t0 = blockIdx.x * 16;
    const int tid = threadIdx.x;
    __shared__ float s[18][D_];
    for (int i = tid; i < 18 * D_ / 4; i += 256) {
        int flat = i * 4;
        int row = flat >> 9;
        int col = flat & (D_ - 1);
        int t = t0 - 1 + row;
        float4 v = make_float4(0.f, 0.f, 0.f, 0.f);
        if (t >= 0 && t < T_)
            v = *reinterpret_cast<const float4*>(ctx + ((size_t)(b * T_ + t)) * D_ + col);
        *reinterpret_cast<float4*>(&s[row][col]) = v;
    }
    __syncthreads();
    float acc[16];
    const float bias = cb[tid];
    #pragma unroll
    for (int i = 0; i < 16; ++i) acc[i] = bias;
    for (int d = 0; d < D_; d += 4) {
        float vv[72];
        #pragma unroll
        for (int r = 0; r < 18; ++r) {
            float4 q = *reinterpret_cast<const float4*>(&s[r][d]);
            vv[r * 4 + 0] = q.x; vv[r * 4 + 1] = q.y;
            vv[r * 4 + 2] = q.z; vv[r * 4 + 3] = q.w;
        }
        #pragma unroll
        for (int sub = 0; sub < 4; ++sub) {
            float w0 = cwT[((d + sub) * 3 + 0) * CO_ + tid];
            float w1 = cwT[((d + sub) * 3 + 1) * CO_ + tid];
            float w2 = cwT[((d + sub) * 3 + 2) * CO_ + tid];
            #pragma unroll
            for (int ti = 0; ti < 16; ++ti) {
                acc[ti] += w0 * vv[(ti + 0) * 4 + sub];
                acc[ti] += w1 * vv[(ti + 1) * 4 + sub];
                acc[ti] += w2 * vv[(ti + 2) * 4 + sub];
            }
        }
    }
    #pragma unroll
    for (int ti = 0; ti < 16; ++ti) {
        ctx2[((size_t)(b * T_ + t0 + ti)) * CO_ + tid] = fmaxf(acc[ti], 0.f);
    }
}

// ---------------- feats + CRF + pooled head ----------------
__global__ __launch_bounds__(256) void k_head(
        const float* __restrict__ ctx2, const float* __restrict__ W_tri,
        const float* __restrict__ b_tri, const float* __restrict__ trans,
        const float* __restrict__ W_lab, const float* __restrict__ b_lab,
        const int* __restrict__ lens, const int* __restrict__ labels,
        float* __restrict__ loss_b, float* __restrict__ spsum_b) {
    const int b = blockIdx.x;
    const int tid = threadIdx.x;
    __shared__ float f_s[T_][4];
    __shared__ float al[T_][4];
    __shared__ float be[T_][4];
    __shared__ float sp_s[T_];
    __shared__ float sv_s[CO_];
    __shared__ float sred[3];
    __shared__ float s_spsum;
    const int len = lens[b];
    for (int idx = tid; idx < T_ * 4; idx += 256) {
        int t = idx >> 2, k = idx & 3;
        const float* row = ctx2 + ((size_t)(b * T_ + t)) * CO_;
        const float* w = W_tri + k * CO_;
        float acc = b_tri[k];
        for (int c = 0; c < CO_; ++c) acc += row[c] * w[c];
        f_s[t][k] = acc;
    }
    __syncthreads();
    if (tid == 0) {
        float Tr[16];
        #pragma unroll
        for (int i = 0; i < 16; ++i) Tr[i] = trans[i];
        float a[4];
        #pragma unroll
        for (int k = 0; k < 4; ++k) { a[k] = f_s[0][k]; al[0][k] = a[k]; }
        for (int t = 1; t < T_; ++t) {
            float an[4];
            #pragma unroll
            for (int j = 0; j < 4; ++j) {
                float m = a[0] + Tr[0 * 4 + j];
                #pragma unroll
                for (int i = 1; i < 4; ++i) m = fmaxf(m, a[i] + Tr[i * 4 + j]);
                float sum = 0.f;
                #pragma unroll
                for (int i = 0; i < 4; ++i) sum += expf(a[i] + Tr[i * 4 + j] - m);
                an[j] = f_s[t][j] + m + logf(sum);
            }
            if (t < len) {
                #pragma unroll
                for (int k = 0; k < 4; ++k) a[k] = an[k];
            }
            #pragma unroll
            for (int k = 0; k < 4; ++k) al[t][k] = a[k];
        }
    } else if (tid == 64) {
        float Tr[16];
        #pragma unroll
        for (int i = 0; i < 16; ++i) Tr[i] = trans[i];
        float bb[4] = {0, 0, 0, 0};
        #pragma unroll
        for (int k = 0; k < 4; ++k) be[T_ - 1][k] = 0.f;
        for (int t = T_ - 2; t >= 0; --t) {
            float bn[4];
            #pragma unroll
            for (int i = 0; i < 4; ++i) {
                float m = Tr[i * 4 + 0] + f_s[t + 1][0] + bb[0];
                #pragma unroll
                for (int j = 1; j < 4; ++j) m = fmaxf(m, Tr[i * 4 + j] + f_s[t + 1][j] + bb[j]);
                float sum = 0.f;
                #pragma unroll
                for (int j = 0; j < 4; ++j) sum += expf(Tr[i * 4 + j] + f_s[t + 1][j] + bb[j] - m);
                bn[i] = m + logf(sum);
            }
            if (t + 1 < len) {
                #pragma unroll
                for (int k = 0; k < 4; ++k) bb[k] = bn[k];
            }
            #pragma unroll
            for (int k = 0; k < 4; ++k) be[t][k] = bb[k];
        }
    }
    __syncthreads();
    if (tid < T_) {
        int t = tid;
        float s0 = al[t][0] + be[t][0];
        float s1 = al[t][1] + be[t][1];
        float s2 = al[t][2] + be[t][2];
        float s3 = al[t][3] + be[t][3];
        float m = fmaxf(fmaxf(s0, s1), fmaxf(s2, s3));
        float e0 = expf(s0 - m), e1 = expf(s1 - m), e2 = expf(s2 - m), e3 = expf(s3 - m);
        float p1 = e1 / (e0 + e1 + e2 + e3);
        sp_s[t] = (t < len) ? p1 : 0.f;
    }
    __syncthreads();
    if (tid == 0) {
        float s = 0.f;
        for (int t = 0; t < T_; ++t) s += sp_s[t];
        s_spsum = s;
    }
    __syncthreads();
    const float spsum = s_spsum;
    {
        float acc = 0.f;
        for (int t = 0; t < T_; ++t)
            acc += sp_s[t] * ctx2[((size_t)(b * T_ + t)) * CO_ + tid];
        sv_s[tid] = acc * 2.f / spsum;
    }
    __syncthreads();
    if (tid < 3) {
        float acc = b_lab[tid];
        const float* w = W_lab + tid * CO_;
        for (int c = 0; c < CO_; ++c) acc += sv_s[c] * w[c];
        sred[tid] = acc;
    }
    __syncthreads();
    if (tid == 0) {
        float m = fmaxf(sred[0], fmaxf(sred[1], sred[2]));
        float lse = m + logf(expf(sred[0] - m) + expf(sred[1] - m) + expf(sred[2] - m));
        loss_b[b] = lse - sred[labels[b]];
        spsum_b[b] = spsum;
    }
}

__global__ void k_final(const float* __restrict__ loss_b, const float* __restrict__ spsum_b,
                        const float* __restrict__ trans, float* __restrict__ out) {
    __shared__ float s1[128], s2[128];
    int tid = threadIdx.x;
    s1[tid] = loss_b[tid];
    s2[tid] = spsum_b[tid];
    __syncthreads();
    for (int off = 64; off > 0; off >>= 1) {
        if (tid < off) { s1[tid] += s1[tid + off]; s2[tid] += s2[tid + off]; }
        __syncthreads();
    }
    if (tid == 0) {
        float pena = fmaxf(trans[1 * 4 + 0] - trans[0 * 4 + 0], 0.f)
                   + fmaxf(trans[0 * 4 + 1] - trans[1 * 4 + 1], 0.f);
        out[0] = s1[0] / (float)B_;
        out[1] = 0.1f * pena + 0.1f * (s2[0] / (float)B_);
    }
}

// ---------------- launch ----------------
extern "C" void kernel_launch(void* const* d_in, const int* in_sizes, int n_in,
                              void* d_out, int out_size, void* d_ws, size_t ws_size,
                              hipStream_t stream) {
    const float* sents   = (const float*)d_in[0];
    const int*   masks   = (const int*)d_in[1];
    const int*   labels  = (const int*)d_in[2];
    const int*   lens    = (const int*)d_in[3];
    const float* mask_emb= (const float*)d_in[4];
    const float* Wih_f   = (const float*)d_in[5];
    const float* Whh_f   = (const float*)d_in[6];
    const float* bih_f   = (const float*)d_in[7];
    const float* bhh_f   = (const float*)d_in[8];
    const float* Wih_b   = (const float*)d_in[9];
    const float* Whh_b   = (const float*)d_in[10];
    const float* bih_b   = (const float*)d_in[11];
    const float* bhh_b   = (const float*)d_in[12];
    const float* conv_w  = (const float*)d_in[13];
    const float* conv_b  = (const float*)d_in[14];
    const float* W_tri   = (const float*)d_in[15];
    const float* b_tri   = (const float*)d_in[16];
    const float* trans   = (const float*)d_in[17];
    const float* W_lab   = (const float*)d_in[18];
    const float* b_lab   = (const float*)d_in[19];
    float* out = (float*)d_out;
    float* ws = (float*)d_ws;

    const size_t o_xgf  = 0;
    const size_t o_xgb  = o_xgf  + (size_t)B_ * T_ * G3_;
    const size_t o_ctx  = o_xgb  + (size_t)B_ * T_ * G3_;   // sents16 then ctx
    const size_t o_ctx2 = o_ctx  + (size_t)B_ * T_ * D_;    // W16 then ctx2
    const size_t o_wp   = o_ctx2 + (size_t)B_ * T_ * CO_;
    const size_t o_me   = o_wp   + (size_t)2 * 32 * 3 * 256 * 4;  // 196608 uints
    const size_t o_cwt  = o_me   + 2 * 2 * G3_;
    const size_t o_lossb= o_cwt  + (size_t)D_ * 3 * CO_;
    const size_t o_spsum= o_lossb + B_;

    float* xgf  = ws + o_xgf;
    float* xgb  = ws + o_xgb;
    float* ctx  = ws + o_ctx;
    float* ctx2 = ws + o_ctx2;
    uint_t* wq  = (uint_t*)(ws + o_wp);
    float* me   = ws + o_me;
    float* cwT  = ws + o_cwt;
    float* lossb = ws + o_lossb;
    float* spsumb = ws + o_spsum;

    _Float16* sents16 = (_Float16*)ctx;
    _Float16* W16 = (_Float16*)ctx2;

    k_prep_me<<<12, 256, 0, stream>>>(mask_emb, Wih_f, bih_f, Wih_b, bih_b, me);
    k_prep_wh<<<768, 256, 0, stream>>>(Whh_f, Whh_b, wq);
    k_tr_cw<<<1536, 256, 0, stream>>>(conv_w, cwT);
    k_cvt_sents<<<8192, 256, 0, stream>>>(sents, (uint_t*)sents16);
    k_cvt_w<<<768, 256, 0, stream>>>(Wih_f, Wih_b, (uint_t*)W16);
    k_gemm_mfma<<<1536, 256, 0, stream>>>(sents16, W16, me, masks, xgf, xgb);
    k_gru<<<dim3(B_, 2), 512, 0, stream>>>(xgf, xgb, wq, bhh_f, bhh_b, lens, ctx);
    k_conv<<<dim3(8, 128), 256, 0, stream>>>(ctx, cwT, conv_b, ctx2);
    k_head<<<128, 256, 0, stream>>>(ctx2, W_tri, b_tri, trans, W_lab, b_lab,
                                    lens, labels, lossb, spsumb);
    k_final<<<1, 128, 0, stream>>>(lossb, spsumb, trans, out);
}

// Round 7
// 552.177 us; speedup vs baseline: 5.4275x; 1.3668x over previous
//
#include <hip/hip_runtime.h>
#include <hip/hip_bf16.h>
#include <math.h>

#define B_ 128
#define T_ 128
#define E_ 1024
#define IN_ 1074
#define H_ 256
#define G3_ 768
#define D_ 512
#define CO_ 256

typedef unsigned int uint_t;
typedef _Float16 v2h __attribute__((ext_vector_type(2)));
typedef _Float16 f16x8 __attribute__((ext_vector_type(8)));
typedef float f32x4 __attribute__((ext_vector_type(4)));

// ---------------- prep kernels ----------------

// me[dir][m][g] = bih[g] + sum_c mask_emb[m][c] * Wih[g][1024+c]
__global__ void k_prep_me(const float* __restrict__ mask_emb,
                          const float* __restrict__ Wf, const float* __restrict__ bf,
                          const float* __restrict__ Wb, const float* __restrict__ bb,
                          float* __restrict__ me) {
    int idx = blockIdx.x * 256 + threadIdx.x;   // 0..3071
    if (idx >= 2 * 2 * G3_) return;
    int dir = idx / (2 * G3_);
    int rem = idx % (2 * G3_);
    int m = rem / G3_;
    int g = rem % G3_;
    const float* W = dir ? Wb : Wf;
    const float* bi = dir ? bb : bf;
    float acc = bi[g];
    const float* wrow = W + (size_t)g * IN_ + E_;
    const float* e = mask_emb + m * 50;
    #pragma unroll 10
    for (int c = 0; c < 50; ++c) acc += e[c] * wrow[c];
    me[idx] = acc;
}

__device__ __forceinline__ uint_t pk2(float a, float b) {
    uint_t u0 = (uint_t)__builtin_bit_cast(unsigned short, (_Float16)a);
    uint_t u1 = (uint_t)__builtin_bit_cast(unsigned short, (_Float16)b);
    return u0 | (u1 << 16);
}

// wq layout: flat[(((d*32+q)*3+p)*256 + j)*4 + u] = pk2(W[g][2kp], W[g][2kp+1])
//   where g = p*256+j, kp = 4q+u (q in [0,32), kp in [0,128)).
__global__ void k_prep_wh(const float* __restrict__ Wf, const float* __restrict__ Wb,
                          uint_t* __restrict__ wq) {
    int idx = blockIdx.x * 256 + threadIdx.x;   // 0..196607
    if (idx >= 196608) return;
    int u = idx & 3;
    int j = (idx >> 2) & 255;
    int rest = idx >> 10;        // (d*32+q)*3+p
    int p = rest % 3;
    int dq = rest / 3;
    int q = dq & 31;
    int d = dq >> 5;
    int g = p * 256 + j;
    int kp = 4 * q + u;          // [0,128)
    const float* W = d ? Wb : Wf;
    float w0 = W[(size_t)g * H_ + 2 * kp];
    float w1 = W[(size_t)g * H_ + 2 * kp + 1];
    wq[idx] = pk2(w0, w1);
}

// W2[co][j*512+d] = f16(conv_w[co][d][j])  -- conv as GEMM weight, K=1536
__global__ void k_prep_w2(const float* __restrict__ cw, unsigned short* __restrict__ W2) {
    int i = blockIdx.x * 256 + threadIdx.x;    // 0..393215
    if (i >= CO_ * 1536) return;
    int co = i / 1536;
    int k = i % 1536;
    int j = k >> 9;          // k / 512
    int d = k & 511;
    float v = cw[(size_t)co * (D_ * 3) + d * 3 + j];
    W2[i] = __builtin_bit_cast(unsigned short, (_Float16)v);
}

// sents f32 -> f16 (packed). 16,777,216 elems, 8 per thread.
__global__ __launch_bounds__(256) void k_cvt_sents(const float* __restrict__ in,
                                                   uint_t* __restrict__ out) {
    int i = blockIdx.x * 256 + threadIdx.x;    // 0..2097151
    float4 a = reinterpret_cast<const float4*>(in)[i * 2];
    float4 b = reinterpret_cast<const float4*>(in)[i * 2 + 1];
    uint4 o;
    o.x = pk2(a.x, a.y); o.y = pk2(a.z, a.w);
    o.z = pk2(b.x, b.y); o.w = pk2(b.z, b.w);
    reinterpret_cast<uint4*>(out)[i] = o;
}

// W16[n][k] = f16(Wih_dir[g][k]), n = dir*768+g, k<1024 (row stride IN_=1074)
__global__ __launch_bounds__(256) void k_cvt_w(const float* __restrict__ Wf,
                                               const float* __restrict__ Wb,
                                               uint_t* __restrict__ out) {
    int i = blockIdx.x * 256 + threadIdx.x;    // 0..196607 (1536*128)
    if (i >= 1536 * 128) return;
    int n = i >> 7, kq = i & 127;
    int dir = n >= G3_;
    int g = n - dir * G3_;
    const float* src = (dir ? Wb : Wf) + (size_t)g * IN_ + kq * 8;
    float2 a = reinterpret_cast<const float2*>(src)[0];
    float2 b = reinterpret_cast<const float2*>(src)[1];
    float2 c = reinterpret_cast<const float2*>(src)[2];
    float2 d = reinterpret_cast<const float2*>(src)[3];
    uint4 o;
    o.x = pk2(a.x, a.y); o.y = pk2(b.x, b.y);
    o.z = pk2(c.x, c.y); o.w = pk2(d.x, d.y);
    reinterpret_cast<uint4*>(out)[i] = o;
}

// ---------------- MFMA xg GEMM ----------------

__device__ __forceinline__ void gload16(const void* g, void* l) {
    __builtin_amdgcn_global_load_lds(
        (const __attribute__((address_space(1))) void*)g,
        (__attribute__((address_space(3))) void*)l, 16, 0, 0);
}

__global__ __launch_bounds__(256) void k_gemm_mfma(
        const _Float16* __restrict__ A16, const _Float16* __restrict__ W16,
        const float* __restrict__ me, const int* __restrict__ masks,
        float* __restrict__ xgf, float* __restrict__ xgb) {
    __shared__ _Float16 As[4096];
    __shared__ _Float16 Bs[4096];
    const int bid = blockIdx.x;
    const int logical = (bid & 7) * 192 + (bid >> 3);   // XCD-contiguous chunks
    const int mt = logical / 12, nt = logical % 12;
    const int bm = mt * 128, bn = nt * 128;
    const int tid = threadIdx.x;
    const int w = tid >> 6, lane = tid & 63;
    const int wr = w >> 1, wc = w & 1;

    const int rl = lane & 15;
    const int kb = (lane >> 4) * 16;
    const int st0 = w, st1 = 4 + w;
    const char* gA0 = (const char*)A16 + (size_t)(bm + st0 * 16 + rl) * 2048 + kb;
    const char* gA1 = (const char*)A16 + (size_t)(bm + st1 * 16 + rl) * 2048 + kb;
    const char* gB0 = (const char*)W16 + (size_t)(bn + st0 * 16 + rl) * 2048 + kb;
    const char* gB1 = (const char*)W16 + (size_t)(bn + st1 * 16 + rl) * 2048 + kb;
    char* lA0 = (char*)As + w * 1024;
    char* lA1 = (char*)As + 4096 + w * 1024;
    char* lB0 = (char*)Bs + w * 1024;
    char* lB1 = (char*)Bs + 4096 + w * 1024;

    f32x4 acc[4][4];
    #pragma unroll
    for (int m = 0; m < 4; ++m)
        #pragma unroll
        for (int n = 0; n < 4; ++n)
            acc[m][n] = (f32x4){0.f, 0.f, 0.f, 0.f};

    for (int kB = 0; kB < 2048; kB += 64) {
        gload16(gA0 + kB, lA0);
        gload16(gA1 + kB, lA1);
        gload16(gB0 + kB, lB0);
        gload16(gB1 + kB, lB1);
        __syncthreads();
        f16x8 af[4], bf[4];
        #pragma unroll
        for (int m = 0; m < 4; ++m)
            af[m] = *reinterpret_cast<const f16x8*>(
                (const char*)As + (wr * 4 + m) * 1024 + lane * 16);
        #pragma unroll
        for (int n = 0; n < 4; ++n)
            bf[n] = *reinterpret_cast<const f16x8*>(
                (const char*)Bs + (wc * 4 + n) * 1024 + lane * 16);
        #pragma unroll
        for (int m = 0; m < 4; ++m)
            #pragma unroll
            for (int n = 0; n < 4; ++n)
                acc[m][n] = __builtin_amdgcn_mfma_f32_16x16x32_f16(
                    af[m], bf[n], acc[m][n], 0, 0, 0);
        __syncthreads();
    }

    const int qr = (lane >> 4) * 4;
    const int cc = lane & 15;
    #pragma unroll
    for (int m = 0; m < 4; ++m) {
        #pragma unroll
        for (int q = 0; q < 4; ++q) {
            const int bt = bm + wr * 64 + m * 16 + qr + q;
            const int mk = masks[bt];
            const int b = bt >> 7, t = bt & 127;
            #pragma unroll
            for (int n = 0; n < 4; ++n) {
                const int col = bn + wc * 64 + n * 16 + cc;
                const int dir = col >= G3_;
                const int g = col - dir * G3_;
                float v = acc[m][n][q] + me[dir * (2 * G3_) + mk * G3_ + g];
                float* dst = (dir ? xgb : xgf) + ((size_t)(t * B_ + b)) * G3_ + g;
                *dst = v;
            }
        }
    }
}

// ---------------- GRU scan (weights in registers) ----------------
__device__ __forceinline__ float dot2(uint_t w, uint_t h, float acc) {
#if __has_builtin(__builtin_amdgcn_fdot2)
    return __builtin_amdgcn_fdot2(__builtin_bit_cast(v2h, w),
                                  __builtin_bit_cast(v2h, h), acc, false);
#else
    v2h a = __builtin_bit_cast(v2h, w), b = __builtin_bit_cast(v2h, h);
    return acc + (float)a[0] * (float)b[0] + (float)a[1] * (float)b[1];
#endif
}

// One block = one (batch row, direction). 512 threads: j = tid&255 owns hidden
// unit j; half = tid>>8 covers k in [half*128, half*128+128). Whh lives in
// 192 VGPRs/thread (48 uint4). Output: f16 into padded ctx16p[b][t+1][dir*256+j].
__global__ __launch_bounds__(512, 2) void k_gru(
        const float* __restrict__ xgf, const float* __restrict__ xgb,
        const uint_t* __restrict__ wq,
        const float* __restrict__ bhhf, const float* __restrict__ bhhb,
        const int* __restrict__ lens, _Float16* __restrict__ ctx16p) {
    const int dir = blockIdx.y;
    const int b = blockIdx.x;
    const int tid = threadIdx.x;
    const int j = tid & 255;
    const int half = tid >> 8;
    const float* xg = dir ? xgb : xgf;
    const float* bhh = dir ? bhhb : bhhf;
    const uint4* wq4 = (const uint4*)wq + (size_t)dir * (32 * 3 * 256);
    _Float16* c16 = ctx16p + (size_t)b * (T_ + 2) * D_;

    __shared__ uint4 hs4[32];            // 256 f16 h values
    __shared__ float part[3][256];
    _Float16* hsf = (_Float16*)hs4;

    // zero the pad rows (both dir-blocks write identical zeros; benign)
    c16[tid] = (_Float16)0.f;                      // row 0 (512 elems)
    c16[(size_t)(T_ + 1) * D_ + tid] = (_Float16)0.f;  // row T+1

    // load weights: w4[p][c] for chunk q = half*16 + c
    uint4 w4[3][16];
    #pragma unroll
    for (int c = 0; c < 16; ++c) {
        const int q = half * 16 + c;
        #pragma unroll
        for (int p = 0; p < 3; ++p)
            w4[p][c] = wq4[((size_t)q * 3 + p) * 256 + j];
    }

    if (tid < 32) hs4[tid] = (uint4){0u, 0u, 0u, 0u};
    const int len = lens[b];
    const float bh0 = bhh[j], bh1 = bhh[H_ + j], bh2 = bhh[2 * H_ + j];
    float hcur = 0.f;
    float g0 = 0.f, g1 = 0.f, g2 = 0.f;
    int t = dir ? (T_ - 1) : 0;
    if (half == 0) {
        const float* r = xg + ((size_t)(t * B_ + b)) * G3_;
        g0 = r[j]; g1 = r[H_ + j]; g2 = r[2 * H_ + j];
    }
    __syncthreads();

    for (int s = 0; s < T_; ++s) {
        const int tn = dir ? (T_ - 2 - s) : (s + 1);
        float n0 = 0.f, n1 = 0.f, n2 = 0.f;
        if (half == 0 && s < T_ - 1) {
            const float* r = xg + ((size_t)(tn * B_ + b)) * G3_;
            n0 = r[j]; n1 = r[H_ + j]; n2 = r[2 * H_ + j];
        }
        float a0 = 0.f, a1 = 0.f, a2 = 0.f;
        #pragma unroll
        for (int c = 0; c < 16; ++c) {
            uint4 hp = hs4[half * 16 + c];
            a0 = dot2(w4[0][c].x, hp.x, a0); a0 = dot2(w4[0][c].y, hp.y, a0);
            a0 = dot2(w4[0][c].z, hp.z, a0); a0 = dot2(w4[0][c].w, hp.w, a0);
            a1 = dot2(w4[1][c].x, hp.x, a1); a1 = dot2(w4[1][c].y, hp.y, a1);
            a1 = dot2(w4[1][c].z, hp.z, a1); a1 = dot2(w4[1][c].w, hp.w, a1);
            a2 = dot2(w4[2][c].x, hp.x, a2); a2 = dot2(w4[2][c].y, hp.y, a2);
            a2 = dot2(w4[2][c].z, hp.z, a2); a2 = dot2(w4[2][c].w, hp.w, a2);
        }
        if (half == 1) {
            part[0][j] = a0; part[1][j] = a1; part[2][j] = a2;
        }
        __syncthreads();
        if (half == 0) {
            a0 += part[0][j]; a1 += part[1][j]; a2 += part[2][j];
            float rg = 1.f / (1.f + expf(-(g0 + a0 + bh0)));
            float zg = 1.f / (1.f + expf(-(g1 + a1 + bh1)));
            float ng = tanhf(g2 + rg * (a2 + bh2));
            float v = (1.f - zg) * ng + zg * hcur;
            hcur = (t < len) ? v : hcur;
            _Float16 h16 = (_Float16)hcur;
            c16[(size_t)(t + 1) * D_ + dir * H_ + j] = h16;
            hsf[j] = h16;
        }
        __syncthreads();
        g0 = n0; g1 = n1; g2 = n2;
        t = tn;
    }
}

// ---------------- conv1d as MFMA GEMM ----------------
// ctx2[b][t][co] = relu( sum_{k<1536} ctx16p[b][t+ k/512][k%512] * W2[co][k] + cb[co] )
// Padded layout makes row t's im2col window the contiguous 1536 f16 at
// ctx16p[b][t][0] (row stride 1024 B). M-tile=128 (=T, one b), N=256 (2 tiles).
__global__ __launch_bounds__(256) void k_conv_mfma(
        const _Float16* __restrict__ C16, const _Float16* __restrict__ W2,
        const float* __restrict__ cb, float* __restrict__ ctx2) {
    __shared__ _Float16 As[4096];
    __shared__ _Float16 Bs[4096];
    const int b = blockIdx.x >> 1;
    const int nt = blockIdx.x & 1;
    const int bn = nt * 128;
    const int tid = threadIdx.x;
    const int w = tid >> 6, lane = tid & 63;
    const int wr = w >> 1, wc = w & 1;
    const int rl = lane & 15;
    const int kb = (lane >> 4) * 16;
    const char* gA0 = (const char*)C16 + ((size_t)(b * (T_ + 2) + w * 16 + rl)) * 1024 + kb;
    const char* gA1 = (const char*)C16 + ((size_t)(b * (T_ + 2) + 64 + w * 16 + rl)) * 1024 + kb;
    const char* gB0 = (const char*)W2 + (size_t)(bn + w * 16 + rl) * 3072 + kb;
    const char* gB1 = (const char*)W2 + (size_t)(bn + 64 + w * 16 + rl) * 3072 + kb;
    char* lA0 = (char*)As + w * 1024;
    char* lA1 = (char*)As + 4096 + w * 1024;
    char* lB0 = (char*)Bs + w * 1024;
    char* lB1 = (char*)Bs + 4096 + w * 1024;

    f32x4 acc[4][4];
    #pragma unroll
    for (int m = 0; m < 4; ++m)
        #pragma unroll
        for (int n = 0; n < 4; ++n)
            acc[m][n] = (f32x4){0.f, 0.f, 0.f, 0.f};

    for (int kB = 0; kB < 3072; kB += 64) {
        gload16(gA0 + kB, lA0);
        gload16(gA1 + kB, lA1);
        gload16(gB0 + kB, lB0);
        gload16(gB1 + kB, lB1);
        __syncthreads();
        f16x8 af[4], bf[4];
        #pragma unroll
        for (int m = 0; m < 4; ++m)
            af[m] = *reinterpret_cast<const f16x8*>(
                (const char*)As + (wr * 4 + m) * 1024 + lane * 16);
        #pragma unroll
        for (int n = 0; n < 4; ++n)
            bf[n] = *reinterpret_cast<const f16x8*>(
                (const char*)Bs + (wc * 4 + n) * 1024 + lane * 16);
        #pragma unroll
        for (int m = 0; m < 4; ++m)
            #pragma unroll
            for (int n = 0; n < 4; ++n)
                acc[m][n] = __builtin_amdgcn_mfma_f32_16x16x32_f16(
                    af[m], bf[n], acc[m][n], 0, 0, 0);
        __syncthreads();
    }

    const int qr = (lane >> 4) * 4;
    const int cc = lane & 15;
    #pragma unroll
    for (int m = 0; m < 4; ++m) {
        #pragma unroll
        for (int q = 0; q < 4; ++q) {
            const int t = wr * 64 + m * 16 + qr + q;
            #pragma unroll
            for (int n = 0; n < 4; ++n) {
                const int co = bn + wc * 64 + n * 16 + cc;
                float v = acc[m][n][q] + cb[co];
                ctx2[((size_t)(b * T_ + t)) * CO_ + co] = fmaxf(v, 0.f);
            }
        }
    }
}

// ---------------- feats + CRF + pooled head ----------------
__global__ __launch_bounds__(256) void k_head(
        const float* __restrict__ ctx2, const float* __restrict__ W_tri,
        const float* __restrict__ b_tri, const float* __restrict__ trans,
        const float* __restrict__ W_lab, const float* __restrict__ b_lab,
        const int* __restrict__ lens, const int* __restrict__ labels,
        float* __restrict__ loss_b, float* __restrict__ spsum_b) {
    const int b = blockIdx.x;
    const int tid = threadIdx.x;
    __shared__ float f_s[T_][4];
    __shared__ float al[T_][4];
    __shared__ float be[T_][4];
    __shared__ float sp_s[T_];
    __shared__ float sv_s[CO_];
    __shared__ float sred[3];
    __shared__ float s_spsum;
    const int len = lens[b];
    for (int idx = tid; idx < T_ * 4; idx += 256) {
        int t = idx >> 2, k = idx & 3;
        const float* row = ctx2 + ((size_t)(b * T_ + t)) * CO_;
        const float* w = W_tri + k * CO_;
        float acc = b_tri[k];
        for (int c = 0; c < CO_; ++c) acc += row[c] * w[c];
        f_s[t][k] = acc;
    }
    __syncthreads();
    if (tid == 0) {
        float Tr[16];
        #pragma unroll
        for (int i = 0; i < 16; ++i) Tr[i] = trans[i];
        float a[4];
        #pragma unroll
        for (int k = 0; k < 4; ++k) { a[k] = f_s[0][k]; al[0][k] = a[k]; }
        for (int t = 1; t < T_; ++t) {
            float an[4];
            #pragma unroll
            for (int j = 0; j < 4; ++j) {
                float m = a[0] + Tr[0 * 4 + j];
                #pragma unroll
                for (int i = 1; i < 4; ++i) m = fmaxf(m, a[i] + Tr[i * 4 + j]);
                float sum = 0.f;
                #pragma unroll
                for (int i = 0; i < 4; ++i) sum += expf(a[i] + Tr[i * 4 + j] - m);
                an[j] = f_s[t][j] + m + logf(sum);
            }
            if (t < len) {
                #pragma unroll
                for (int k = 0; k < 4; ++k) a[k] = an[k];
            }
            #pragma unroll
            for (int k = 0; k < 4; ++k) al[t][k] = a[k];
        }
    } else if (tid == 64) {
        float Tr[16];
        #pragma unroll
        for (int i = 0; i < 16; ++i) Tr[i] = trans[i];
        float bb[4] = {0, 0, 0, 0};
        #pragma unroll
        for (int k = 0; k < 4; ++k) be[T_ - 1][k] = 0.f;
        for (int t = T_ - 2; t >= 0; --t) {
            float bn[4];
            #pragma unroll
            for (int i = 0; i < 4; ++i) {
                float m = Tr[i * 4 + 0] + f_s[t + 1][0] + bb[0];
                #pragma unroll
                for (int j = 1; j < 4; ++j) m = fmaxf(m, Tr[i * 4 + j] + f_s[t + 1][j] + bb[j]);
                float sum = 0.f;
                #pragma unroll
                for (int j = 0; j < 4; ++j) sum += expf(Tr[i * 4 + j] + f_s[t + 1][j] + bb[j] - m);
                bn[i] = m + logf(sum);
            }
            if (t + 1 < len) {
                #pragma unroll
                for (int k = 0; k < 4; ++k) bb[k] = bn[k];
            }
            #pragma unroll
            for (int k = 0; k < 4; ++k) be[t][k] = bb[k];
        }
    }
    __syncthreads();
    if (tid < T_) {
        int t = tid;
        float s0 = al[t][0] + be[t][0];
        float s1 = al[t][1] + be[t][1];
        float s2 = al[t][2] + be[t][2];
        float s3 = al[t][3] + be[t][3];
        float m = fmaxf(fmaxf(s0, s1), fmaxf(s2, s3));
        float e0 = expf(s0 - m), e1 = expf(s1 - m), e2 = expf(s2 - m), e3 = expf(s3 - m);
        float p1 = e1 / (e0 + e1 + e2 + e3);
        sp_s[t] = (t < len) ? p1 : 0.f;
    }
    __syncthreads();
    if (tid == 0) {
        float s = 0.f;
        for (int t = 0; t < T_; ++t) s += sp_s[t];
        s_spsum = s;
    }
    __syncthreads();
    const float spsum = s_spsum;
    {
        float acc = 0.f;
        for (int t = 0; t < T_; ++t)
            acc += sp_s[t] * ctx2[((size_t)(b * T_ + t)) * CO_ + tid];
        sv_s[tid] = acc * 2.f / spsum;
    }
    __syncthreads();
    if (tid < 3) {
        float acc = b_lab[tid];
        const float* w = W_lab + tid * CO_;
        for (int c = 0; c < CO_; ++c) acc += sv_s[c] * w[c];
        sred[tid] = acc;
    }
    __syncthreads();
    if (tid == 0) {
        float m = fmaxf(sred[0], fmaxf(sred[1], sred[2]));
        float lse = m + logf(expf(sred[0] - m) + expf(sred[1] - m) + expf(sred[2] - m));
        loss_b[b] = lse - sred[labels[b]];
        spsum_b[b] = spsum;
    }
}

__global__ void k_final(const float* __restrict__ loss_b, const float* __restrict__ spsum_b,
                        const float* __restrict__ trans, float* __restrict__ out) {
    __shared__ float s1[128], s2[128];
    int tid = threadIdx.x;
    s1[tid] = loss_b[tid];
    s2[tid] = spsum_b[tid];
    __syncthreads();
    for (int off = 64; off > 0; off >>= 1) {
        if (tid < off) { s1[tid] += s1[tid + off]; s2[tid] += s2[tid + off]; }
        __syncthreads();
    }
    if (tid == 0) {
        float pena = fmaxf(trans[1 * 4 + 0] - trans[0 * 4 + 0], 0.f)
                   + fmaxf(trans[0 * 4 + 1] - trans[1 * 4 + 1], 0.f);
        out[0] = s1[0] / (float)B_;
        out[1] = 0.1f * pena + 0.1f * (s2[0] / (float)B_);
    }
}

// ---------------- launch ----------------
extern "C" void kernel_launch(void* const* d_in, const int* in_sizes, int n_in,
                              void* d_out, int out_size, void* d_ws, size_t ws_size,
                              hipStream_t stream) {
    const float* sents   = (const float*)d_in[0];
    const int*   masks   = (const int*)d_in[1];
    const int*   labels  = (const int*)d_in[2];
    const int*   lens    = (const int*)d_in[3];
    const float* mask_emb= (const float*)d_in[4];
    const float* Wih_f   = (const float*)d_in[5];
    const float* Whh_f   = (const float*)d_in[6];
    const float* bih_f   = (const float*)d_in[7];
    const float* bhh_f   = (const float*)d_in[8];
    const float* Wih_b   = (const float*)d_in[9];
    const float* Whh_b   = (const float*)d_in[10];
    const float* bih_b   = (const float*)d_in[11];
    const float* bhh_b   = (const float*)d_in[12];
    const float* conv_w  = (const float*)d_in[13];
    const float* conv_b  = (const float*)d_in[14];
    const float* W_tri   = (const float*)d_in[15];
    const float* b_tri   = (const float*)d_in[16];
    const float* trans   = (const float*)d_in[17];
    const float* W_lab   = (const float*)d_in[18];
    const float* b_lab   = (const float*)d_in[19];
    float* out = (float*)d_out;
    float* ws = (float*)d_ws;

    const size_t o_xgf  = 0;
    const size_t o_xgb  = o_xgf  + (size_t)B_ * T_ * G3_;
    const size_t o_ctx  = o_xgb  + (size_t)B_ * T_ * G3_;   // sents16, then ctx16p
    const size_t o_ctx2 = o_ctx  + (size_t)B_ * T_ * D_;    // W16, then ctx2 f32
    const size_t o_wp   = o_ctx2 + (size_t)B_ * T_ * CO_;
    const size_t o_me   = o_wp   + (size_t)2 * 32 * 3 * 256 * 4;  // 196608 uints
    const size_t o_w2   = o_me   + 2 * 2 * G3_;
    const size_t o_lossb= o_w2   + (size_t)D_ * 3 * CO_;
    const size_t o_spsum= o_lossb + B_;

    float* xgf  = ws + o_xgf;
    float* xgb  = ws + o_xgb;
    float* ctx  = ws + o_ctx;
    float* ctx2 = ws + o_ctx2;
    uint_t* wq  = (uint_t*)(ws + o_wp);
    float* me   = ws + o_me;
    unsigned short* W2 = (unsigned short*)(ws + o_w2);
    float* lossb = ws + o_lossb;
    float* spsumb = ws + o_spsum;

    // region reuse: sents16 (33.5MB) lives in o_ctx until gemm consumes it; then
    // k_gru writes ctx16p (17MB, padded [B][T+2][D] f16) into the same region.
    _Float16* sents16 = (_Float16*)ctx;
    _Float16* ctx16p = (_Float16*)ctx;
    _Float16* W16 = (_Float16*)ctx2;    // consumed by gemm before ctx2 written

    k_prep_me<<<12, 256, 0, stream>>>(mask_emb, Wih_f, bih_f, Wih_b, bih_b, me);
    k_prep_wh<<<768, 256, 0, stream>>>(Whh_f, Whh_b, wq);
    k_prep_w2<<<1536, 256, 0, stream>>>(conv_w, W2);
    k_cvt_sents<<<8192, 256, 0, stream>>>(sents, (uint_t*)sents16);
    k_cvt_w<<<768, 256, 0, stream>>>(Wih_f, Wih_b, (uint_t*)W16);
    k_gemm_mfma<<<1536, 256, 0, stream>>>(sents16, W16, me, masks, xgf, xgb);
    k_gru<<<dim3(B_, 2), 512, 0, stream>>>(xgf, xgb, wq, bhh_f, bhh_b, lens, ctx16p);
    k_conv_mfma<<<256, 256, 0, stream>>>(ctx16p, (const _Float16*)W2, conv_b, ctx2);
    k_head<<<128, 256, 0, stream>>>(ctx2, W_tri, b_tri, trans, W_lab, b_lab,
                                    lens, labels, lossb, spsumb);
    k_final<<<1, 128, 0, stream>>>(lossb, spsumb, trans, out);
}

// Round 8
// 418.261 us; speedup vs baseline: 7.1653x; 1.3202x over previous
//
#include <hip/hip_runtime.h>
#include <hip/hip_bf16.h>
#include <math.h>

#define B_ 128
#define T_ 128
#define E_ 1024
#define IN_ 1074
#define H_ 256
#define G3_ 768
#define D_ 512
#define CO_ 256

typedef unsigned int uint_t;
typedef _Float16 v2h __attribute__((ext_vector_type(2)));
typedef _Float16 f16x8 __attribute__((ext_vector_type(8)));
typedef float f32x4 __attribute__((ext_vector_type(4)));

// ---------------- prep kernels ----------------

// me[dir][m][g] = bih[g] + sum_c mask_emb[m][c] * Wih[g][1024+c]
__global__ void k_prep_me(const float* __restrict__ mask_emb,
                          const float* __restrict__ Wf, const float* __restrict__ bf,
                          const float* __restrict__ Wb, const float* __restrict__ bb,
                          float* __restrict__ me) {
    int idx = blockIdx.x * 256 + threadIdx.x;   // 0..3071
    if (idx >= 2 * 2 * G3_) return;
    int dir = idx / (2 * G3_);
    int rem = idx % (2 * G3_);
    int m = rem / G3_;
    int g = rem % G3_;
    const float* W = dir ? Wb : Wf;
    const float* bi = dir ? bb : bf;
    float acc = bi[g];
    const float* wrow = W + (size_t)g * IN_ + E_;
    const float* e = mask_emb + m * 50;
    #pragma unroll 10
    for (int c = 0; c < 50; ++c) acc += e[c] * wrow[c];
    me[idx] = acc;
}

__device__ __forceinline__ uint_t pk2(float a, float b) {
    uint_t u0 = (uint_t)__builtin_bit_cast(unsigned short, (_Float16)a);
    uint_t u1 = (uint_t)__builtin_bit_cast(unsigned short, (_Float16)b);
    return u0 | (u1 << 16);
}

// wq layout: flat[(((d*32+q)*3+p)*256 + j)*4 + u] = pk2(W[g][2kp], W[g][2kp+1])
//   where g = p*256+j, kp = 4q+u (q in [0,32), kp in [0,128)).
__global__ void k_prep_wh(const float* __restrict__ Wf, const float* __restrict__ Wb,
                          uint_t* __restrict__ wq) {
    int idx = blockIdx.x * 256 + threadIdx.x;   // 0..196607
    if (idx >= 196608) return;
    int u = idx & 3;
    int j = (idx >> 2) & 255;
    int rest = idx >> 10;        // (d*32+q)*3+p
    int p = rest % 3;
    int dq = rest / 3;
    int q = dq & 31;
    int d = dq >> 5;
    int g = p * 256 + j;
    int kp = 4 * q + u;          // [0,128)
    const float* W = d ? Wb : Wf;
    float w0 = W[(size_t)g * H_ + 2 * kp];
    float w1 = W[(size_t)g * H_ + 2 * kp + 1];
    wq[idx] = pk2(w0, w1);
}

// W2[co][j*512+d] = f16(conv_w[co][d][j])  -- conv as GEMM weight, K=1536
__global__ void k_prep_w2(const float* __restrict__ cw, unsigned short* __restrict__ W2) {
    int i = blockIdx.x * 256 + threadIdx.x;    // 0..393215
    if (i >= CO_ * 1536) return;
    int co = i / 1536;
    int k = i % 1536;
    int j = k >> 9;          // k / 512
    int d = k & 511;
    float v = cw[(size_t)co * (D_ * 3) + d * 3 + j];
    W2[i] = __builtin_bit_cast(unsigned short, (_Float16)v);
}

// sents f32 -> f16 (packed). 16,777,216 elems, 8 per thread.
__global__ __launch_bounds__(256) void k_cvt_sents(const float* __restrict__ in,
                                                   uint_t* __restrict__ out) {
    int i = blockIdx.x * 256 + threadIdx.x;    // 0..2097151
    float4 a = reinterpret_cast<const float4*>(in)[i * 2];
    float4 b = reinterpret_cast<const float4*>(in)[i * 2 + 1];
    uint4 o;
    o.x = pk2(a.x, a.y); o.y = pk2(a.z, a.w);
    o.z = pk2(b.x, b.y); o.w = pk2(b.z, b.w);
    reinterpret_cast<uint4*>(out)[i] = o;
}

// W16[n][k] = f16(Wih_dir[g][k]), n = dir*768+g, k<1024 (row stride IN_=1074)
__global__ __launch_bounds__(256) void k_cvt_w(const float* __restrict__ Wf,
                                               const float* __restrict__ Wb,
                                               uint_t* __restrict__ out) {
    int i = blockIdx.x * 256 + threadIdx.x;    // 0..196607 (1536*128)
    if (i >= 1536 * 128) return;
    int n = i >> 7, kq = i & 127;
    int dir = n >= G3_;
    int g = n - dir * G3_;
    const float* src = (dir ? Wb : Wf) + (size_t)g * IN_ + kq * 8;
    float2 a = reinterpret_cast<const float2*>(src)[0];
    float2 b = reinterpret_cast<const float2*>(src)[1];
    float2 c = reinterpret_cast<const float2*>(src)[2];
    float2 d = reinterpret_cast<const float2*>(src)[3];
    uint4 o;
    o.x = pk2(a.x, a.y); o.y = pk2(b.x, b.y);
    o.z = pk2(c.x, c.y); o.w = pk2(d.x, d.y);
    reinterpret_cast<uint4*>(out)[i] = o;
}

// ---------------- MFMA xg GEMM ----------------

__device__ __forceinline__ void gload16(const void* g, void* l) {
    __builtin_amdgcn_global_load_lds(
        (const __attribute__((address_space(1))) void*)g,
        (__attribute__((address_space(3))) void*)l, 16, 0, 0);
}

__global__ __launch_bounds__(256) void k_gemm_mfma(
        const _Float16* __restrict__ A16, const _Float16* __restrict__ W16,
        const float* __restrict__ me, const int* __restrict__ masks,
        float* __restrict__ xgf, float* __restrict__ xgb) {
    __shared__ _Float16 As[4096];
    __shared__ _Float16 Bs[4096];
    const int bid = blockIdx.x;
    const int logical = (bid & 7) * 192 + (bid >> 3);   // XCD-contiguous chunks
    const int mt = logical / 12, nt = logical % 12;
    const int bm = mt * 128, bn = nt * 128;
    const int tid = threadIdx.x;
    const int w = tid >> 6, lane = tid & 63;
    const int wr = w >> 1, wc = w & 1;

    const int rl = lane & 15;
    const int kb = (lane >> 4) * 16;
    const int st0 = w, st1 = 4 + w;
    const char* gA0 = (const char*)A16 + (size_t)(bm + st0 * 16 + rl) * 2048 + kb;
    const char* gA1 = (const char*)A16 + (size_t)(bm + st1 * 16 + rl) * 2048 + kb;
    const char* gB0 = (const char*)W16 + (size_t)(bn + st0 * 16 + rl) * 2048 + kb;
    const char* gB1 = (const char*)W16 + (size_t)(bn + st1 * 16 + rl) * 2048 + kb;
    char* lA0 = (char*)As + w * 1024;
    char* lA1 = (char*)As + 4096 + w * 1024;
    char* lB0 = (char*)Bs + w * 1024;
    char* lB1 = (char*)Bs + 4096 + w * 1024;

    f32x4 acc[4][4];
    #pragma unroll
    for (int m = 0; m < 4; ++m)
        #pragma unroll
        for (int n = 0; n < 4; ++n)
            acc[m][n] = (f32x4){0.f, 0.f, 0.f, 0.f};

    for (int kB = 0; kB < 2048; kB += 64) {
        gload16(gA0 + kB, lA0);
        gload16(gA1 + kB, lA1);
        gload16(gB0 + kB, lB0);
        gload16(gB1 + kB, lB1);
        __syncthreads();
        f16x8 af[4], bf[4];
        #pragma unroll
        for (int m = 0; m < 4; ++m)
            af[m] = *reinterpret_cast<const f16x8*>(
                (const char*)As + (wr * 4 + m) * 1024 + lane * 16);
        #pragma unroll
        for (int n = 0; n < 4; ++n)
            bf[n] = *reinterpret_cast<const f16x8*>(
                (const char*)Bs + (wc * 4 + n) * 1024 + lane * 16);
        #pragma unroll
        for (int m = 0; m < 4; ++m)
            #pragma unroll
            for (int n = 0; n < 4; ++n)
                acc[m][n] = __builtin_amdgcn_mfma_f32_16x16x32_f16(
                    af[m], bf[n], acc[m][n], 0, 0, 0);
        __syncthreads();
    }

    const int qr = (lane >> 4) * 4;
    const int cc = lane & 15;
    #pragma unroll
    for (int m = 0; m < 4; ++m) {
        #pragma unroll
        for (int q = 0; q < 4; ++q) {
            const int bt = bm + wr * 64 + m * 16 + qr + q;
            const int mk = masks[bt];
            const int b = bt >> 7, t = bt & 127;
            #pragma unroll
            for (int n = 0; n < 4; ++n) {
                const int col = bn + wc * 64 + n * 16 + cc;
                const int dir = col >= G3_;
                const int g = col - dir * G3_;
                float v = acc[m][n][q] + me[dir * (2 * G3_) + mk * G3_ + g];
                float* dst = (dir ? xgb : xgf) + ((size_t)(t * B_ + b)) * G3_ + g;
                *dst = v;
            }
        }
    }
}

// ---------------- GRU scan (weights in registers) ----------------
__device__ __forceinline__ float dot2(uint_t w, uint_t h, float acc) {
#if __has_builtin(__builtin_amdgcn_fdot2)
    return __builtin_amdgcn_fdot2(__builtin_bit_cast(v2h, w),
                                  __builtin_bit_cast(v2h, h), acc, false);
#else
    v2h a = __builtin_bit_cast(v2h, w), b = __builtin_bit_cast(v2h, h);
    return acc + (float)a[0] * (float)b[0] + (float)a[1] * (float)b[1];
#endif
}

// One block = one (batch row, direction). 512 threads: j = tid&255 owns hidden
// unit j; half = tid>>8 covers k in [half*128, half*128+128). Whh lives in
// 192 VGPRs/thread (48 uint4). Output: f16 into padded ctx16p[b][t+1][dir*256+j].
__global__ __launch_bounds__(512, 2) void k_gru(
        const float* __restrict__ xgf, const float* __restrict__ xgb,
        const uint_t* __restrict__ wq,
        const float* __restrict__ bhhf, const float* __restrict__ bhhb,
        const int* __restrict__ lens, _Float16* __restrict__ ctx16p) {
    const int dir = blockIdx.y;
    const int b = blockIdx.x;
    const int tid = threadIdx.x;
    const int j = tid & 255;
    const int half = tid >> 8;
    const float* xg = dir ? xgb : xgf;
    const float* bhh = dir ? bhhb : bhhf;
    const uint4* wq4 = (const uint4*)wq + (size_t)dir * (32 * 3 * 256);
    _Float16* c16 = ctx16p + (size_t)b * (T_ + 2) * D_;

    __shared__ uint4 hs4[32];            // 256 f16 h values
    __shared__ float part[3][256];
    _Float16* hsf = (_Float16*)hs4;

    // zero the pad rows (both dir-blocks write identical zeros; benign)
    c16[tid] = (_Float16)0.f;                      // row 0 (512 elems)
    c16[(size_t)(T_ + 1) * D_ + tid] = (_Float16)0.f;  // row T+1

    // load weights: w4[p][c] for chunk q = half*16 + c
    uint4 w4[3][16];
    #pragma unroll
    for (int c = 0; c < 16; ++c) {
        const int q = half * 16 + c;
        #pragma unroll
        for (int p = 0; p < 3; ++p)
            w4[p][c] = wq4[((size_t)q * 3 + p) * 256 + j];
    }

    if (tid < 32) hs4[tid] = (uint4){0u, 0u, 0u, 0u};
    const int len = lens[b];
    const float bh0 = bhh[j], bh1 = bhh[H_ + j], bh2 = bhh[2 * H_ + j];
    float hcur = 0.f;
    float g0 = 0.f, g1 = 0.f, g2 = 0.f;
    int t = dir ? (T_ - 1) : 0;
    if (half == 0) {
        const float* r = xg + ((size_t)(t * B_ + b)) * G3_;
        g0 = r[j]; g1 = r[H_ + j]; g2 = r[2 * H_ + j];
    }
    __syncthreads();

    for (int s = 0; s < T_; ++s) {
        const int tn = dir ? (T_ - 2 - s) : (s + 1);
        float n0 = 0.f, n1 = 0.f, n2 = 0.f;
        if (half == 0 && s < T_ - 1) {
            const float* r = xg + ((size_t)(tn * B_ + b)) * G3_;
            n0 = r[j]; n1 = r[H_ + j]; n2 = r[2 * H_ + j];
        }
        float a0 = 0.f, a1 = 0.f, a2 = 0.f;
        #pragma unroll
        for (int c = 0; c < 16; ++c) {
            uint4 hp = hs4[half * 16 + c];
            a0 = dot2(w4[0][c].x, hp.x, a0); a0 = dot2(w4[0][c].y, hp.y, a0);
            a0 = dot2(w4[0][c].z, hp.z, a0); a0 = dot2(w4[0][c].w, hp.w, a0);
            a1 = dot2(w4[1][c].x, hp.x, a1); a1 = dot2(w4[1][c].y, hp.y, a1);
            a1 = dot2(w4[1][c].z, hp.z, a1); a1 = dot2(w4[1][c].w, hp.w, a1);
            a2 = dot2(w4[2][c].x, hp.x, a2); a2 = dot2(w4[2][c].y, hp.y, a2);
            a2 = dot2(w4[2][c].z, hp.z, a2); a2 = dot2(w4[2][c].w, hp.w, a2);
        }
        if (half == 1) {
            part[0][j] = a0; part[1][j] = a1; part[2][j] = a2;
        }
        __syncthreads();
        if (half == 0) {
            a0 += part[0][j]; a1 += part[1][j]; a2 += part[2][j];
            float rg = 1.f / (1.f + expf(-(g0 + a0 + bh0)));
            float zg = 1.f / (1.f + expf(-(g1 + a1 + bh1)));
            float ng = tanhf(g2 + rg * (a2 + bh2));
            float v = (1.f - zg) * ng + zg * hcur;
            hcur = (t < len) ? v : hcur;
            _Float16 h16 = (_Float16)hcur;
            c16[(size_t)(t + 1) * D_ + dir * H_ + j] = h16;
            hsf[j] = h16;
        }
        __syncthreads();
        g0 = n0; g1 = n1; g2 = n2;
        t = tn;
    }
}

// ---------------- conv1d as MFMA GEMM ----------------
__global__ __launch_bounds__(256) void k_conv_mfma(
        const _Float16* __restrict__ C16, const _Float16* __restrict__ W2,
        const float* __restrict__ cb, float* __restrict__ ctx2) {
    __shared__ _Float16 As[4096];
    __shared__ _Float16 Bs[4096];
    const int b = blockIdx.x >> 1;
    const int nt = blockIdx.x & 1;
    const int bn = nt * 128;
    const int tid = threadIdx.x;
    const int w = tid >> 6, lane = tid & 63;
    const int wr = w >> 1, wc = w & 1;
    const int rl = lane & 15;
    const int kb = (lane >> 4) * 16;
    const char* gA0 = (const char*)C16 + ((size_t)(b * (T_ + 2) + w * 16 + rl)) * 1024 + kb;
    const char* gA1 = (const char*)C16 + ((size_t)(b * (T_ + 2) + 64 + w * 16 + rl)) * 1024 + kb;
    const char* gB0 = (const char*)W2 + (size_t)(bn + w * 16 + rl) * 3072 + kb;
    const char* gB1 = (const char*)W2 + (size_t)(bn + 64 + w * 16 + rl) * 3072 + kb;
    char* lA0 = (char*)As + w * 1024;
    char* lA1 = (char*)As + 4096 + w * 1024;
    char* lB0 = (char*)Bs + w * 1024;
    char* lB1 = (char*)Bs + 4096 + w * 1024;

    f32x4 acc[4][4];
    #pragma unroll
    for (int m = 0; m < 4; ++m)
        #pragma unroll
        for (int n = 0; n < 4; ++n)
            acc[m][n] = (f32x4){0.f, 0.f, 0.f, 0.f};

    for (int kB = 0; kB < 3072; kB += 64) {
        gload16(gA0 + kB, lA0);
        gload16(gA1 + kB, lA1);
        gload16(gB0 + kB, lB0);
        gload16(gB1 + kB, lB1);
        __syncthreads();
        f16x8 af[4], bf[4];
        #pragma unroll
        for (int m = 0; m < 4; ++m)
            af[m] = *reinterpret_cast<const f16x8*>(
                (const char*)As + (wr * 4 + m) * 1024 + lane * 16);
        #pragma unroll
        for (int n = 0; n < 4; ++n)
            bf[n] = *reinterpret_cast<const f16x8*>(
                (const char*)Bs + (wc * 4 + n) * 1024 + lane * 16);
        #pragma unroll
        for (int m = 0; m < 4; ++m)
            #pragma unroll
            for (int n = 0; n < 4; ++n)
                acc[m][n] = __builtin_amdgcn_mfma_f32_16x16x32_f16(
                    af[m], bf[n], acc[m][n], 0, 0, 0);
        __syncthreads();
    }

    const int qr = (lane >> 4) * 4;
    const int cc = lane & 15;
    #pragma unroll
    for (int m = 0; m < 4; ++m) {
        #pragma unroll
        for (int q = 0; q < 4; ++q) {
            const int t = wr * 64 + m * 16 + qr + q;
            #pragma unroll
            for (int n = 0; n < 4; ++n) {
                const int co = bn + wc * 64 + n * 16 + cc;
                float v = acc[m][n][q] + cb[co];
                ctx2[((size_t)(b * T_ + t)) * CO_ + co] = fmaxf(v, 0.f);
            }
        }
    }
}

// ---------------- feats + CRF + pooled head (wave-parallel) ----------------
__global__ __launch_bounds__(256) void k_head(
        const float* __restrict__ ctx2, const float* __restrict__ W_tri,
        const float* __restrict__ b_tri, const float* __restrict__ trans,
        const float* __restrict__ W_lab, const float* __restrict__ b_lab,
        const int* __restrict__ lens, const int* __restrict__ labels,
        float* __restrict__ loss_b, float* __restrict__ spsum_b) {
    const int b = blockIdx.x;
    const int tid = threadIdx.x;
    const int w = tid >> 6, lane = tid & 63;
    __shared__ float f_s[T_][4];
    __shared__ float al[T_][4];
    __shared__ float be[T_][4];
    __shared__ float sp_s[T_];
    __shared__ float sv_s[CO_];
    __shared__ float sred[4];
    __shared__ float s_spsum;
    const int len = lens[b];
    const float* base = ctx2 + (size_t)b * T_ * CO_;

    // ---- phase A: feats[t][k] — wave-parallel dot products ----
    {
        float wt[4][4];
        #pragma unroll
        for (int k = 0; k < 4; ++k)
            #pragma unroll
            for (int q = 0; q < 4; ++q)
                wt[k][q] = W_tri[k * CO_ + lane + 64 * q];
        float bt0 = b_tri[0], bt1 = b_tri[1], bt2 = b_tri[2], bt3 = b_tri[3];
        for (int t = w; t < T_; t += 4) {
            const float* row = base + (size_t)t * CO_;
            float v0 = row[lane], v1 = row[lane + 64],
                  v2 = row[lane + 128], v3 = row[lane + 192];
            float p0 = v0 * wt[0][0] + v1 * wt[0][1] + v2 * wt[0][2] + v3 * wt[0][3];
            float p1 = v0 * wt[1][0] + v1 * wt[1][1] + v2 * wt[1][2] + v3 * wt[1][3];
            float p2 = v0 * wt[2][0] + v1 * wt[2][1] + v2 * wt[2][2] + v3 * wt[2][3];
            float p3 = v0 * wt[3][0] + v1 * wt[3][1] + v2 * wt[3][2] + v3 * wt[3][3];
            #pragma unroll
            for (int off = 32; off > 0; off >>= 1) {
                p0 += __shfl_xor(p0, off);
                p1 += __shfl_xor(p1, off);
                p2 += __shfl_xor(p2, off);
                p3 += __shfl_xor(p3, off);
            }
            if (lane == 0) {
                f_s[t][0] = p0 + bt0; f_s[t][1] = p1 + bt1;
                f_s[t][2] = p2 + bt2; f_s[t][3] = p3 + bt3;
            }
        }
    }
    __syncthreads();

    // ---- phase B: CRF scans, 4 lanes each (wave 0 fwd, wave 1 bwd) ----
    if (w == 0 && lane < 4) {
        const int j = lane;
        float tc0 = trans[0 * 4 + j], tc1 = trans[1 * 4 + j],
              tc2 = trans[2 * 4 + j], tc3 = trans[3 * 4 + j];
        float a = f_s[0][j];
        al[0][j] = a;
        for (int t = 1; t < T_; ++t) {
            float a0 = __shfl(a, 0), a1 = __shfl(a, 1),
                  a2 = __shfl(a, 2), a3 = __shfl(a, 3);
            float s0 = a0 + tc0, s1 = a1 + tc1, s2 = a2 + tc2, s3 = a3 + tc3;
            float m = fmaxf(fmaxf(s0, s1), fmaxf(s2, s3));
            float sum = expf(s0 - m) + expf(s1 - m) + expf(s2 - m) + expf(s3 - m);
            float an = f_s[t][j] + m + logf(sum);
            if (t < len) a = an;
            al[t][j] = a;
        }
    } else if (w == 1 && lane < 4) {
        const int i = lane;
        float tr0 = trans[i * 4 + 0], tr1 = trans[i * 4 + 1],
              tr2 = trans[i * 4 + 2], tr3 = trans[i * 4 + 3];
        float bb = 0.f;
        be[T_ - 1][i] = 0.f;
        for (int t = T_ - 2; t >= 0; --t) {
            float b0 = __shfl(bb, 0), b1 = __shfl(bb, 1),
                  b2 = __shfl(bb, 2), b3 = __shfl(bb, 3);
            float s0 = tr0 + f_s[t + 1][0] + b0;
            float s1 = tr1 + f_s[t + 1][1] + b1;
            float s2 = tr2 + f_s[t + 1][2] + b2;
            float s3 = tr3 + f_s[t + 1][3] + b3;
            float m = fmaxf(fmaxf(s0, s1), fmaxf(s2, s3));
            float sum = expf(s0 - m) + expf(s1 - m) + expf(s2 - m) + expf(s3 - m);
            float bn = m + logf(sum);
            if (t + 1 < len) bb = bn;
            be[t][i] = bb;
        }
    }
    __syncthreads();

    // ---- phase C: marginals sp[t] + spsum ----
    if (tid < T_) {
        int t = tid;
        float s0 = al[t][0] + be[t][0];
        float s1 = al[t][1] + be[t][1];
        float s2 = al[t][2] + be[t][2];
        float s3 = al[t][3] + be[t][3];
        float m = fmaxf(fmaxf(s0, s1), fmaxf(s2, s3));
        float e0 = expf(s0 - m), e1 = expf(s1 - m), e2 = expf(s2 - m), e3 = expf(s3 - m);
        float p1 = e1 / (e0 + e1 + e2 + e3);
        sp_s[t] = (t < len) ? p1 : 0.f;
    }
    __syncthreads();
    if (w == 0) {
        float s = sp_s[lane] + sp_s[lane + 64];
        #pragma unroll
        for (int off = 32; off > 0; off >>= 1) s += __shfl_xor(s, off);
        if (lane == 0) s_spsum = s;
    }
    __syncthreads();
    const float spsum = s_spsum;

    // ---- phase D: pooled sent_v (thread = channel) ----
    {
        float acc0 = 0.f, acc1 = 0.f, acc2 = 0.f, acc3 = 0.f;
        #pragma unroll 2
        for (int t = 0; t < T_; t += 4) {
            acc0 += sp_s[t + 0] * base[(size_t)(t + 0) * CO_ + tid];
            acc1 += sp_s[t + 1] * base[(size_t)(t + 1) * CO_ + tid];
            acc2 += sp_s[t + 2] * base[(size_t)(t + 2) * CO_ + tid];
            acc3 += sp_s[t + 3] * base[(size_t)(t + 3) * CO_ + tid];
        }
        sv_s[tid] = (acc0 + acc1 + acc2 + acc3) * 2.f / spsum;
    }
    __syncthreads();

    // ---- phase E: class scores (3 waves) + loss ----
    if (w < 3) {
        const float* wl = W_lab + w * CO_;
        float p = sv_s[lane] * wl[lane] + sv_s[lane + 64] * wl[lane + 64]
                + sv_s[lane + 128] * wl[lane + 128] + sv_s[lane + 192] * wl[lane + 192];
        #pragma unroll
        for (int off = 32; off > 0; off >>= 1) p += __shfl_xor(p, off);
        if (lane == 0) sred[w] = p + b_lab[w];
    }
    __syncthreads();
    if (tid == 0) {
        float m = fmaxf(sred[0], fmaxf(sred[1], sred[2]));
        float lse = m + logf(expf(sred[0] - m) + expf(sred[1] - m) + expf(sred[2] - m));
        loss_b[b] = lse - sred[labels[b]];
        spsum_b[b] = spsum;
    }
}

__global__ void k_final(const float* __restrict__ loss_b, const float* __restrict__ spsum_b,
                        const float* __restrict__ trans, float* __restrict__ out) {
    __shared__ float s1[128], s2[128];
    int tid = threadIdx.x;
    s1[tid] = loss_b[tid];
    s2[tid] = spsum_b[tid];
    __syncthreads();
    for (int off = 64; off > 0; off >>= 1) {
        if (tid < off) { s1[tid] += s1[tid + off]; s2[tid] += s2[tid + off]; }
        __syncthreads();
    }
    if (tid == 0) {
        float pena = fmaxf(trans[1 * 4 + 0] - trans[0 * 4 + 0], 0.f)
                   + fmaxf(trans[0 * 4 + 1] - trans[1 * 4 + 1], 0.f);
        out[0] = s1[0] / (float)B_;
        out[1] = 0.1f * pena + 0.1f * (s2[0] / (float)B_);
    }
}

// ---------------- launch ----------------
extern "C" void kernel_launch(void* const* d_in, const int* in_sizes, int n_in,
                              void* d_out, int out_size, void* d_ws, size_t ws_size,
                              hipStream_t stream) {
    const float* sents   = (const float*)d_in[0];
    const int*   masks   = (const int*)d_in[1];
    const int*   labels  = (const int*)d_in[2];
    const int*   lens    = (const int*)d_in[3];
    const float* mask_emb= (const float*)d_in[4];
    const float* Wih_f   = (const float*)d_in[5];
    const float* Whh_f   = (const float*)d_in[6];
    const float* bih_f   = (const float*)d_in[7];
    const float* bhh_f   = (const float*)d_in[8];
    const float* Wih_b   = (const float*)d_in[9];
    const float* Whh_b   = (const float*)d_in[10];
    const float* bih_b   = (const float*)d_in[11];
    const float* bhh_b   = (const float*)d_in[12];
    const float* conv_w  = (const float*)d_in[13];
    const float* conv_b  = (const float*)d_in[14];
    const float* W_tri   = (const float*)d_in[15];
    const float* b_tri   = (const float*)d_in[16];
    const float* trans   = (const float*)d_in[17];
    const float* W_lab   = (const float*)d_in[18];
    const float* b_lab   = (const float*)d_in[19];
    float* out = (float*)d_out;
    float* ws = (float*)d_ws;

    const size_t o_xgf  = 0;
    const size_t o_xgb  = o_xgf  + (size_t)B_ * T_ * G3_;
    const size_t o_ctx  = o_xgb  + (size_t)B_ * T_ * G3_;   // sents16, then ctx16p
    const size_t o_ctx2 = o_ctx  + (size_t)B_ * T_ * D_;    // W16, then ctx2 f32
    const size_t o_wp   = o_ctx2 + (size_t)B_ * T_ * CO_;
    const size_t o_me   = o_wp   + (size_t)2 * 32 * 3 * 256 * 4;  // 196608 uints
    const size_t o_w2   = o_me   + 2 * 2 * G3_;
    const size_t o_lossb= o_w2   + (size_t)D_ * 3 * CO_;
    const size_t o_spsum= o_lossb + B_;

    float* xgf  = ws + o_xgf;
    float* xgb  = ws + o_xgb;
    float* ctx  = ws + o_ctx;
    float* ctx2 = ws + o_ctx2;
    uint_t* wq  = (uint_t*)(ws + o_wp);
    float* me   = ws + o_me;
    unsigned short* W2 = (unsigned short*)(ws + o_w2);
    float* lossb = ws + o_lossb;
    float* spsumb = ws + o_spsum;

    _Float16* sents16 = (_Float16*)ctx;
    _Float16* ctx16p = (_Float16*)ctx;
    _Float16* W16 = (_Float16*)ctx2;    // consumed by gemm before ctx2 written

    k_prep_me<<<12, 256, 0, stream>>>(mask_emb, Wih_f, bih_f, Wih_b, bih_b, me);
    k_prep_wh<<<768, 256, 0, stream>>>(Whh_f, Whh_b, wq);
    k_prep_w2<<<1536, 256, 0, stream>>>(conv_w, W2);
    k_cvt_sents<<<8192, 256, 0, stream>>>(sents, (uint_t*)sents16);
    k_cvt_w<<<768, 256, 0, stream>>>(Wih_f, Wih_b, (uint_t*)W16);
    k_gemm_mfma<<<1536, 256, 0, stream>>>(sents16, W16, me, masks, xgf, xgb);
    k_gru<<<dim3(B_, 2), 512, 0, stream>>>(xgf, xgb, wq, bhh_f, bhh_b, lens, ctx16p);
    k_conv_mfma<<<256, 256, 0, stream>>>(ctx16p, (const _Float16*)W2, conv_b, ctx2);
    k_head<<<128, 256, 0, stream>>>(ctx2, W_tri, b_tri, trans, W_lab, b_lab,
                                    lens, labels, lossb, spsumb);
    k_final<<<1, 128, 0, stream>>>(lossb, spsumb, trans, out);
}